// Round 9
// baseline (296.792 us; speedup 1.0000x reference)
//
#include <hip/hip_runtime.h>
#include <hip/hip_bf16.h>

// Model: one_hot -> 3x Conv2D(5,(4,4),(1,2),SAME) -> [B,S=1024,D=20]
//        -> 3x causal self-attention -> flatten -> 3x Dense(10)
// B=64, L=8192, S=1024, D=20.
// Attention + QKV projection use bf16 MFMA (16x16x32, D padded to K=32).
// Scores |s|<<1 -> streaming softmax needs no max-subtraction (exact fp32
// C-frag accumulation). Convs/dense fp32.

#define B_ 64
#define L_ 8192
#define S_ 1024
#define D_ 20

typedef unsigned short ushort_t;
typedef __attribute__((ext_vector_type(8))) short short8_t;  // 8 bf16 (4 VGPRs)
typedef __attribute__((ext_vector_type(4))) float f32x4_t;   // MFMA C/D

__device__ __forceinline__ ushort_t f2bf(float f) {          // RNE fp32->bf16
  unsigned u = __float_as_uint(f);
  return (ushort_t)((u + 0x7fffu + ((u >> 16) & 1u)) >> 16);
}
__device__ __forceinline__ float bf2f(ushort_t h) {
  return __uint_as_float(((unsigned)h) << 16);
}

// ---------------- conv1: one-hot input, CI=1 ----------------
__global__ __launch_bounds__(256) void conv1_kernel(
    const int* __restrict__ inp, const float* __restrict__ W,
    const float* __restrict__ Bi, float* __restrict__ out) {
  __shared__ float ws[80];
  __shared__ float bs[5];
  if (threadIdx.x < 80) ws[threadIdx.x] = W[threadIdx.x];
  if (threadIdx.x < 5)  bs[threadIdx.x] = Bi[threadIdx.x];
  __syncthreads();
  int idx = blockIdx.x * 256 + threadIdx.x;   // (b, wo), wo in [0,4096)
  int b  = idx >> 12;
  int wo = idx & 4095;
  float acc[4][5];
#pragma unroll
  for (int h = 0; h < 4; ++h)
#pragma unroll
    for (int c = 0; c < 5; ++c) acc[h][c] = bs[c];
  const int* ib = inp + (size_t)b * L_;
#pragma unroll
  for (int kw = 0; kw < 4; ++kw) {
    int wi = 2 * wo - 1 + kw;
    if (wi >= 0 && wi < L_) {
      int v = ib[wi];
#pragma unroll
      for (int h = 0; h < 4; ++h) {
        int kh = v - h + 1;
        if (kh >= 0 && kh < 4) {
#pragma unroll
          for (int c = 0; c < 5; ++c) acc[h][c] += ws[(kh * 4 + kw) * 5 + c];
        }
      }
    }
  }
  float* ob = out + (size_t)b * 4 * 4096 * 5;
#pragma unroll
  for (int h = 0; h < 4; ++h)
#pragma unroll
    for (int c = 0; c < 5; ++c) ob[(h * 4096 + wo) * 5 + c] = acc[h][c];
}

// ---------------- conv2/conv3: LDS-staged input slab ----------------
// Block = (wo-chunk of 256, b). Input slab [4 hi][516 wi][5 ci] staged with
// fully-coalesced dword loads (OOB -> 0 at staging = SAME padding, no
// per-lane branches in compute). Per-thread window = 20 contiguous LDS
// floats per hi. Weights broadcast from LDS as before.
template <int WIN, bool TRANS>
__global__ __launch_bounds__(256) void conv5_kernel(
    const float* __restrict__ in, const float* __restrict__ W,
    const float* __restrict__ Bi, float* __restrict__ out) {
  constexpr int WOUT = WIN / 2;
  constexpr int PFL  = 2580;            // 516 positions * 5 ci floats per hi
  __shared__ float ws[400];
  __shared__ float bs[5];
  __shared__ float slab[4 * PFL];       // 41.3 KB
  for (int j = threadIdx.x; j < 400; j += 256) ws[j] = W[j];
  if (threadIdx.x < 5) bs[threadIdx.x] = Bi[threadIdx.x];
  const int wo0 = blockIdx.x * 256;
  const int b   = blockIdx.y;
  const int f0  = (2 * wo0 - 1) * 5;    // global float offset of slab start
#pragma unroll
  for (int hi = 0; hi < 4; ++hi) {
    const float* ir = in + ((size_t)b * 4 + hi) * WIN * 5;
    for (int idx = threadIdx.x; idx < PFL; idx += 256) {
      int gf = f0 + idx;
      slab[hi * PFL + idx] = (gf >= 0 && gf < WIN * 5) ? ir[gf] : 0.f;
    }
  }
  __syncthreads();
  const int tid = threadIdx.x;
  const int wo  = wo0 + tid;
  float val[4][4][5];
#pragma unroll
  for (int hi = 0; hi < 4; ++hi) {
    const float* sl = slab + hi * PFL + 10 * tid;  // 20 contiguous floats
#pragma unroll
    for (int kw = 0; kw < 4; ++kw)
#pragma unroll
      for (int ci = 0; ci < 5; ++ci) val[hi][kw][ci] = sl[kw * 5 + ci];
  }
  float acc[4][5];
#pragma unroll
  for (int h = 0; h < 4; ++h)
#pragma unroll
    for (int c = 0; c < 5; ++c) acc[h][c] = bs[c];
#pragma unroll
  for (int kh = 0; kh < 4; ++kh)
#pragma unroll
    for (int kw = 0; kw < 4; ++kw)
#pragma unroll
      for (int ci = 0; ci < 5; ++ci) {
        const float* wp = ws + ((kh * 4 + kw) * 5 + ci) * 5;
        float w0 = wp[0], w1 = wp[1], w2 = wp[2], w3 = wp[3], w4 = wp[4];
#pragma unroll
        for (int h = 0; h < 4; ++h) {
          int hi = h - 1 + kh;
          if (hi >= 0 && hi < 4) {
            float x = val[hi][kw][ci];
            acc[h][0] += w0 * x; acc[h][1] += w1 * x; acc[h][2] += w2 * x;
            acc[h][3] += w3 * x; acc[h][4] += w4 * x;
          }
        }
      }
  if (TRANS) {
    float* ob = out + ((size_t)b * WOUT + wo) * 20;
#pragma unroll
    for (int h = 0; h < 4; ++h)
#pragma unroll
      for (int c = 0; c < 5; ++c) ob[h * 5 + c] = acc[h][c];
  } else {
    float* ob = out + (size_t)b * 4 * WOUT * 5;
#pragma unroll
    for (int h = 0; h < 4; ++h)
#pragma unroll
      for (int c = 0; c < 5; ++c) ob[(h * WOUT + wo) * 5 + c] = acc[h][c];
  }
}

// ---------------- Q/K/V projection via MFMA ----------------
// GEMM: X[65536 x 20] x Wcat[20 x 60] where Wcat cols = [K(20)|Q(20)|V(20)|0(4)],
// Q pre-scaled by 1/sqrt(20). B-operand tile (lane n = out-col n, k=quad*8+j)
// built per block in LDS (stride 40 us -> <=2-way banks). A-frag: X row ->
// bf16 on the fly (k>=20 zero). Outputs: qb/kb [r][32] bf16 (k 20..31 zeroed
// here — ALL 6 pad dwords per row; R8's n<3 fill left 26..30 as garbage ->
// 1e8-scale bf16 reinterpret -> exp(inf) NaN), vt [b][32][1024] bf16 d-major.
__global__ __launch_bounds__(256) void proj_mfma(
    const float* __restrict__ X,
    const float* __restrict__ Kw, const float* __restrict__ Qw,
    const float* __restrict__ Vw,
    ushort_t* __restrict__ Qb, ushort_t* __restrict__ Kb,
    ushort_t* __restrict__ Vt) {
  __shared__ ushort_t wt[64 * 40];      // [out-col][k], k 0..31 used
  const float sc = 0.22360679774997896f;
  for (int e = threadIdx.x; e < 2048; e += 256) {
    int col = e >> 5, k = e & 31;
    float v = 0.f;
    if (k < 20) {
      if (col < 20)      v = Kw[k * 20 + col];
      else if (col < 40) v = Qw[k * 20 + (col - 20)] * sc;
      else if (col < 60) v = Vw[k * 20 + (col - 40)];
    }
    wt[col * 40 + k] = f2bf(v);
  }
  __syncthreads();
  const int tid  = threadIdx.x;
  const int w    = tid >> 6;
  const int lane = tid & 63;
  const int n    = lane & 15;
  const int quad = lane >> 4;
  const int base = blockIdx.x * 64;           // 64 rows per block
  // A-frag: row base+16w+n, k = quad*8..+8 (fp32 -> bf16, k>=20 zero)
  const float* xr = X + (size_t)(base + 16 * w + n) * D_;
  ushort_t ah[8];
#pragma unroll
  for (int j = 0; j < 8; ++j) {
    int k = quad * 8 + j;
    ah[j] = (k < D_) ? f2bf(xr[k]) : (ushort_t)0;
  }
  short8_t afrag = *(const short8_t*)ah;
  const f32x4_t zero = {0.f, 0.f, 0.f, 0.f};
  const int rbase = base + 16 * w + quad * 4;  // C rows rbase..rbase+3
  const int bb = rbase >> 10, s0 = rbase & 1023;
#pragma unroll
  for (int t = 0; t < 4; ++t) {
    const short8_t bfrag = *(const short8_t*)(wt + (t * 16 + n) * 40 + quad * 8);
    f32x4_t c = __builtin_amdgcn_mfma_f32_16x16x32_bf16(afrag, bfrag, zero, 0, 0, 0);
    const int col = t * 16 + n;
    if (col < 20) {
#pragma unroll
      for (int r = 0; r < 4; ++r) Kb[(size_t)(rbase + r) * 32 + col] = f2bf(c[r]);
    } else if (col < 40) {
#pragma unroll
      for (int r = 0; r < 4; ++r) Qb[(size_t)(rbase + r) * 32 + (col - 20)] = f2bf(c[r]);
    } else if (col < 60) {
      const int d = col - 40;
      unsigned lo = (unsigned)f2bf(c[0]) | ((unsigned)f2bf(c[1]) << 16);
      unsigned hi = (unsigned)f2bf(c[2]) | ((unsigned)f2bf(c[3]) << 16);
      uint2 pv = make_uint2(lo, hi);
      *(uint2*)(Vt + (size_t)bb * 32768 + (size_t)d * 1024 + s0) = pv;
    }
  }
  // zero-fill qb/kb k = 20..31: 6 dwords per row per tensor (ushort offsets
  // 20,22,24,26,28,30). Lanes n 0..5 -> Kb, n 6..11 -> Qb.
#pragma unroll
  for (int r = 0; r < 4; ++r) {
    if (n < 6)       *(unsigned*)(Kb + (size_t)(rbase + r) * 32 + 20 + 2 * n) = 0u;
    else if (n < 12) *(unsigned*)(Qb + (size_t)(rbase + r) * 32 + 20 + 2 * (n - 6)) = 0u;
  }
}

// ---------------- causal attention via bf16 MFMA ----------------
// 16 strips of 64 q-rows per batch. Strip swizzle: co-resident blocks are
// stride-256 apart, so strip = (bx + 4*(by>>4)) & 15 gives each CU strips
// {c,c+4,c+8,c+12} (CU load 28..40 tile-units -> makespan 1.18x not 1.9x).
// Wave w owns rows qbase=q0+16w..+15 (A-frag: row=lane&15, k=quad*8+j).
// Per 128-t staged tile: 4 chunks of 32 t. Chunk: 2 QK MFMAs (t-halves),
// exp+mask on C-frags (row=quad*4+reg, col=lane&15), P->LDS->A-frag
// round-trip (wave-synchronous, lgkmcnt fence), 2 PV MFMAs. l accumulated
// from bf16-rounded P so normalization cancels rounding. No max-subtraction
// needed (|s|<<1). O in fp32 C-frags.
#define TT_ 128
__global__ __launch_bounds__(256) void attn_kernel(
    const ushort_t* __restrict__ Qb, const ushort_t* __restrict__ Kb,
    const ushort_t* __restrict__ Vt, float* __restrict__ out) {
  const int b     = blockIdx.y;
  const int strip = (blockIdx.x + 4 * (blockIdx.y >> 4)) & 15;
  const int q0    = strip * 64;
  const int tid   = threadIdx.x;
  const int w     = tid >> 6;             // wave 0..3
  const int lane  = tid & 63;
  const int n     = lane & 15;
  const int quad  = lane >> 4;
  const int qbase = q0 + 16 * w;
  __shared__ ushort_t kts[128 * 40];      // K tile, row stride 40 us (80 B)
  __shared__ ushort_t vts[32 * 136];      // V^T tile, row stride 136 us (272 B)
  __shared__ ushort_t pts[4][16 * 40];    // per-wave P scratch, stride 40 us
  const ushort_t* KbB = Kb + (size_t)b * 1024 * 32;
  const ushort_t* VtB = Vt + (size_t)b * 32 * 1024;
  short8_t qfrag = *(const short8_t*)(Qb + ((size_t)(b * 1024 + qbase + n)) * 32 + quad * 8);
  f32x4_t oA = {0.f, 0.f, 0.f, 0.f};
  f32x4_t oB = {0.f, 0.f, 0.f, 0.f};
  f32x4_t lac = {0.f, 0.f, 0.f, 0.f};
  const f32x4_t zero = {0.f, 0.f, 0.f, 0.f};
  const int Tw = qbase + 16;              // exclusive t bound for this wave
  const int nt = q0 + 64;                 // block-uniform staging bound
  ushort_t* prow = pts[w];
  for (int t0 = 0; t0 < nt; t0 += TT_) {
    __syncthreads();
    for (int i = tid; i < 512; i += 256) {
      int row = i >> 2, qc = i & 3;
      *(int4*)(kts + row * 40 + qc * 8) =
          *(const int4*)(KbB + (size_t)(t0 + row) * 32 + qc * 8);
    }
    for (int i = tid; i < 320; i += 256) {
      int row = i >> 4, cc = i & 15;
      *(int4*)(vts + row * 136 + cc * 8) =
          *(const int4*)(VtB + (size_t)row * 1024 + t0 + cc * 8);
    }
    __syncthreads();
#pragma unroll 1
    for (int cc = 0; cc < 4; ++cc) {
      const int tc = t0 + cc * 32;
      if (tc >= Tw) break;                // wave-uniform
      const short8_t kfA = *(const short8_t*)(kts + (cc * 32 + n) * 40 + quad * 8);
      const short8_t kfB = *(const short8_t*)(kts + (cc * 32 + 16 + n) * 40 + quad * 8);
      f32x4_t sA = __builtin_amdgcn_mfma_f32_16x16x32_bf16(qfrag, kfA, zero, 0, 0, 0);
      f32x4_t sB = __builtin_amdgcn_mfma_f32_16x16x32_bf16(qfrag, kfB, zero, 0, 0, 0);
#pragma unroll
      for (int r = 0; r < 4; ++r) {
        const int qg = qbase + quad * 4 + r;
        float pA = (tc + n      <= qg) ? __expf(sA[r]) : 0.f;
        float pB = (tc + 16 + n <= qg) ? __expf(sB[r]) : 0.f;
        ushort_t hA = f2bf(pA), hB = f2bf(pB);
        lac[r] += bf2f(hA) + bf2f(hB);    // consistent with bf16 P used in PV
        prow[(quad * 4 + r) * 40 + n]      = hA;
        prow[(quad * 4 + r) * 40 + 16 + n] = hB;
      }
      __asm__ volatile("s_waitcnt lgkmcnt(0)" ::: "memory");  // wave-sync LDS RAW
      short8_t pfrag = *(const short8_t*)(prow + n * 40 + quad * 8);
      const short8_t vfA = *(const short8_t*)(vts + n * 136 + cc * 32 + quad * 8);
      const short8_t vfB = *(const short8_t*)(vts + (16 + n) * 136 + cc * 32 + quad * 8);
      oA = __builtin_amdgcn_mfma_f32_16x16x32_bf16(pfrag, vfA, oA, 0, 0, 0);
      oB = __builtin_amdgcn_mfma_f32_16x16x32_bf16(pfrag, vfB, oB, 0, 0, 0);
    }
  }
#pragma unroll
  for (int m = 1; m <= 8; m <<= 1) {
#pragma unroll
    for (int r = 0; r < 4; ++r) lac[r] += __shfl_xor(lac[r], m, 64);
  }
  float* ob = out + ((size_t)(b * 1024 + qbase)) * 20;
#pragma unroll
  for (int r = 0; r < 4; ++r) {
    const float inv = 1.f / lac[r];
    const int qq = quad * 4 + r;
    ob[qq * 20 + n] = oA[r] * inv;                    // d = 0..15
    if (n < 4) ob[qq * 20 + 16 + n] = oB[r] * inv;    // d = 16..19
  }
}

// ---------------- W1 transpose (once per call) ----------------
__global__ __launch_bounds__(256) void transpose_w1(
    const float* __restrict__ W1,   // [20480, 10]
    float* __restrict__ W1T) {      // [10, 20480]
  int idx = blockIdx.x * 256 + threadIdx.x;        // 204800 total
  int j = idx / 20480;
  int i = idx % 20480;
  W1T[idx] = W1[i * 10 + j];
}

// ---------------- dense head: stage 1 (partials, vectorized) ----------------
__global__ __launch_bounds__(256) void dense1_partial(
    const float* __restrict__ X,    // [64, 20480]
    const float* __restrict__ W1T,  // [10, 20480]
    float* __restrict__ part) {     // [64, 4, 10]
  const int b = blockIdx.x;
  const int s = blockIdx.y;
  const float4* xb = (const float4*)(X + (size_t)b * 20480 + s * 5120);
  float acc[10];
#pragma unroll
  for (int j = 0; j < 10; ++j) acc[j] = 0.f;
  for (int i = threadIdx.x; i < 1280; i += 256) {
    float4 xv = xb[i];
#pragma unroll
    for (int j = 0; j < 10; ++j) {
      float4 wv = ((const float4*)(W1T + (size_t)j * 20480 + s * 5120))[i];
      acc[j] += xv.x * wv.x + xv.y * wv.y + xv.z * wv.z + xv.w * wv.w;
    }
  }
  __shared__ float red[256][10];
#pragma unroll
  for (int j = 0; j < 10; ++j) red[threadIdx.x][j] = acc[j];
  __syncthreads();
  for (int off = 128; off > 0; off >>= 1) {
    if (threadIdx.x < (unsigned)off) {
#pragma unroll
      for (int j = 0; j < 10; ++j) red[threadIdx.x][j] += red[threadIdx.x + off][j];
    }
    __syncthreads();
  }
  if (threadIdx.x < 10) part[(b * 4 + s) * 10 + threadIdx.x] = red[0][threadIdx.x];
}

// ---------------- dense head: stage 2 (combine + dense2/3) ----------------
__global__ __launch_bounds__(64) void dense_final(
    const float* __restrict__ part,
    const float* __restrict__ B1,
    const float* __restrict__ W2, const float* __restrict__ B2,
    const float* __restrict__ W3, const float* __restrict__ B3,
    float* __restrict__ out) {
  const int b = blockIdx.x;
  __shared__ float y1[10], y2[10];
  if (threadIdx.x < 10) {
    int j = threadIdx.x;
    y1[j] = part[(b*4+0)*10 + j] + part[(b*4+1)*10 + j] +
            part[(b*4+2)*10 + j] + part[(b*4+3)*10 + j] + B1[j];
  }
  __syncthreads();
  if (threadIdx.x < 10) {
    int j = threadIdx.x;
    float s = B2[j];
#pragma unroll
    for (int i = 0; i < 10; ++i) s += y1[i] * W2[i * 10 + j];
    y2[j] = s;
  }
  __syncthreads();
  if (threadIdx.x < 10) {
    int j = threadIdx.x;
    float s = B3[j];
#pragma unroll
    for (int i = 0; i < 10; ++i) s += y2[i] * W3[i * 10 + j];
    out[b * 10 + j] = s;
  }
}

extern "C" void kernel_launch(void* const* d_in, const int* in_sizes, int n_in,
                              void* d_out, int out_size, void* d_ws, size_t ws_size,
                              hipStream_t stream) {
  const int*   inp = (const int*)d_in[0];
  const float* cw1 = (const float*)d_in[1];
  const float* cb1 = (const float*)d_in[2];
  const float* cw2 = (const float*)d_in[3];
  const float* cb2 = (const float*)d_in[4];
  const float* cw3 = (const float*)d_in[5];
  const float* cb3 = (const float*)d_in[6];
  const float* a1K = (const float*)d_in[7];
  const float* a1Q = (const float*)d_in[8];
  const float* a1V = (const float*)d_in[9];
  const float* a2K = (const float*)d_in[10];
  const float* a2Q = (const float*)d_in[11];
  const float* a2V = (const float*)d_in[12];
  const float* a3K = (const float*)d_in[13];
  const float* a3Q = (const float*)d_in[14];
  const float* a3V = (const float*)d_in[15];
  const float* dw1 = (const float*)d_in[16];
  const float* db1 = (const float*)d_in[17];
  const float* dw2 = (const float*)d_in[18];
  const float* db2 = (const float*)d_in[19];
  const float* dw3 = (const float*)d_in[20];
  const float* db3 = (const float*)d_in[21];
  float* outp = (float*)d_out;

  // workspace layout (float units)
  float* wsf = (float*)d_ws;
  float*    c1   = wsf;                         // [B,4,4096,5]   [0 .. 5,242,880)
  float*    c2   = wsf + 5242880;               // [B,4,2048,5]   [5,242,880 .. 7,864,320)
  float*    x    = wsf + 7864320;               // [B,S,20]       [7,864,320 .. 9,175,040)
  ushort_t* qb   = (ushort_t*)(wsf);            // [B,S,32] bf16  [0 .. 1,048,576) fl
  ushort_t* kb   = (ushort_t*)(wsf + 1048576);  //                [1,048,576 .. 2,097,152)
  ushort_t* vt   = (ushort_t*)(wsf + 2097152);  // [B,32,S] bf16  [2,097,152 .. 3,145,728)
  float*    o    = wsf + 3145728;               // [B,S,20]       [3,145,728 .. 4,456,448)
  float*    part = wsf + 4456448;               // [64,4,10]      2,560 floats
  float*    w1t  = wsf + 4459008;               // [10, 20480]    204,800 floats

  conv1_kernel<<<1024, 256, 0, stream>>>(inp, cw1, cb1, c1);
  conv5_kernel<4096, false><<<dim3(8, 64), 256, 0, stream>>>(c1, cw2, cb2, c2);
  conv5_kernel<2048, true><<<dim3(4, 64), 256, 0, stream>>>(c2, cw3, cb3, x);
  // c1 dead from here; qb/kb/vt/o live in its footprint.
  transpose_w1<<<800, 256, 0, stream>>>(dw1, w1t);

  proj_mfma<<<1024, 256, 0, stream>>>(x, a1K, a1Q, a1V, qb, kb, vt);
  attn_kernel<<<dim3(16, 64), 256, 0, stream>>>(qb, kb, vt, o);

  proj_mfma<<<1024, 256, 0, stream>>>(o, a2K, a2Q, a2V, qb, kb, vt);
  attn_kernel<<<dim3(16, 64), 256, 0, stream>>>(qb, kb, vt, x);

  proj_mfma<<<1024, 256, 0, stream>>>(x, a3K, a3Q, a3V, qb, kb, vt);
  attn_kernel<<<dim3(16, 64), 256, 0, stream>>>(qb, kb, vt, o);

  dense1_partial<<<dim3(64, 4), 256, 0, stream>>>(o, w1t, part);
  dense_final<<<64, 64, 0, stream>>>(part, db1, dw2, db2, dw3, db3, outp);
}

// Round 10
// 295.372 us; speedup vs baseline: 1.0048x; 1.0048x over previous
//
#include <hip/hip_runtime.h>
#include <hip/hip_bf16.h>

// Model: one_hot -> 3x Conv2D(5,(4,4),(1,2),SAME) -> [B,S=1024,D=20]
//        -> 3x causal self-attention -> flatten -> 3x Dense(10)
// B=64, L=8192, S=1024, D=20.
// Attention uses bf16 MFMA (16x16x32, D padded to K=32). Scores |s|<<1 ->
// streaming softmax needs no max-subtraction (exact fp32 C-frag accumulation).
// Convs/proj/dense fp32. (R10: proj_mfma reverted to R7 proj_kernel — its
// 4-MFMA-per-wave tile couldn't amortize staging+divergent epilogue.)

#define B_ 64
#define L_ 8192
#define S_ 1024
#define D_ 20

typedef unsigned short ushort_t;
typedef __attribute__((ext_vector_type(8))) short short8_t;  // 8 bf16 (4 VGPRs)
typedef __attribute__((ext_vector_type(4))) float f32x4_t;   // MFMA C/D

__device__ __forceinline__ ushort_t f2bf(float f) {          // RNE fp32->bf16
  unsigned u = __float_as_uint(f);
  return (ushort_t)((u + 0x7fffu + ((u >> 16) & 1u)) >> 16);
}
__device__ __forceinline__ float bf2f(ushort_t h) {
  return __uint_as_float(((unsigned)h) << 16);
}

// ---------------- conv1: one-hot input, CI=1 ----------------
__global__ __launch_bounds__(256) void conv1_kernel(
    const int* __restrict__ inp, const float* __restrict__ W,
    const float* __restrict__ Bi, float* __restrict__ out) {
  __shared__ float ws[80];
  __shared__ float bs[5];
  if (threadIdx.x < 80) ws[threadIdx.x] = W[threadIdx.x];
  if (threadIdx.x < 5)  bs[threadIdx.x] = Bi[threadIdx.x];
  __syncthreads();
  int idx = blockIdx.x * 256 + threadIdx.x;   // (b, wo), wo in [0,4096)
  int b  = idx >> 12;
  int wo = idx & 4095;
  float acc[4][5];
#pragma unroll
  for (int h = 0; h < 4; ++h)
#pragma unroll
    for (int c = 0; c < 5; ++c) acc[h][c] = bs[c];
  const int* ib = inp + (size_t)b * L_;
#pragma unroll
  for (int kw = 0; kw < 4; ++kw) {
    int wi = 2 * wo - 1 + kw;
    if (wi >= 0 && wi < L_) {
      int v = ib[wi];
#pragma unroll
      for (int h = 0; h < 4; ++h) {
        int kh = v - h + 1;
        if (kh >= 0 && kh < 4) {
#pragma unroll
          for (int c = 0; c < 5; ++c) acc[h][c] += ws[(kh * 4 + kw) * 5 + c];
        }
      }
    }
  }
  float* ob = out + (size_t)b * 4 * 4096 * 5;
#pragma unroll
  for (int h = 0; h < 4; ++h)
#pragma unroll
    for (int c = 0; c < 5; ++c) ob[(h * 4096 + wo) * 5 + c] = acc[h][c];
}

// ---------------- conv2/conv3: LDS-staged input slab ----------------
// Block = (wo-chunk of 256, b). Input slab [4 hi][516 wi][5 ci] staged with
// fully-coalesced dword loads (OOB -> 0 at staging = SAME padding).
// Per-thread window = 20 contiguous LDS floats per hi.
template <int WIN, bool TRANS>
__global__ __launch_bounds__(256) void conv5_kernel(
    const float* __restrict__ in, const float* __restrict__ W,
    const float* __restrict__ Bi, float* __restrict__ out) {
  constexpr int WOUT = WIN / 2;
  constexpr int PFL  = 2580;            // 516 positions * 5 ci floats per hi
  __shared__ float ws[400];
  __shared__ float bs[5];
  __shared__ float slab[4 * PFL];       // 41.3 KB
  for (int j = threadIdx.x; j < 400; j += 256) ws[j] = W[j];
  if (threadIdx.x < 5) bs[threadIdx.x] = Bi[threadIdx.x];
  const int wo0 = blockIdx.x * 256;
  const int b   = blockIdx.y;
  const int f0  = (2 * wo0 - 1) * 5;    // global float offset of slab start
#pragma unroll
  for (int hi = 0; hi < 4; ++hi) {
    const float* ir = in + ((size_t)b * 4 + hi) * WIN * 5;
    for (int idx = threadIdx.x; idx < PFL; idx += 256) {
      int gf = f0 + idx;
      slab[hi * PFL + idx] = (gf >= 0 && gf < WIN * 5) ? ir[gf] : 0.f;
    }
  }
  __syncthreads();
  const int tid = threadIdx.x;
  const int wo  = wo0 + tid;
  float val[4][4][5];
#pragma unroll
  for (int hi = 0; hi < 4; ++hi) {
    const float* sl = slab + hi * PFL + 10 * tid;  // 20 contiguous floats
#pragma unroll
    for (int kw = 0; kw < 4; ++kw)
#pragma unroll
      for (int ci = 0; ci < 5; ++ci) val[hi][kw][ci] = sl[kw * 5 + ci];
  }
  float acc[4][5];
#pragma unroll
  for (int h = 0; h < 4; ++h)
#pragma unroll
    for (int c = 0; c < 5; ++c) acc[h][c] = bs[c];
#pragma unroll
  for (int kh = 0; kh < 4; ++kh)
#pragma unroll
    for (int kw = 0; kw < 4; ++kw)
#pragma unroll
      for (int ci = 0; ci < 5; ++ci) {
        const float* wp = ws + ((kh * 4 + kw) * 5 + ci) * 5;
        float w0 = wp[0], w1 = wp[1], w2 = wp[2], w3 = wp[3], w4 = wp[4];
#pragma unroll
        for (int h = 0; h < 4; ++h) {
          int hi = h - 1 + kh;
          if (hi >= 0 && hi < 4) {
            float x = val[hi][kw][ci];
            acc[h][0] += w0 * x; acc[h][1] += w1 * x; acc[h][2] += w2 * x;
            acc[h][3] += w3 * x; acc[h][4] += w4 * x;
          }
        }
      }
  if (TRANS) {
    float* ob = out + ((size_t)b * WOUT + wo) * 20;
#pragma unroll
    for (int h = 0; h < 4; ++h)
#pragma unroll
      for (int c = 0; c < 5; ++c) ob[h * 5 + c] = acc[h][c];
  } else {
    float* ob = out + (size_t)b * 4 * WOUT * 5;
#pragma unroll
    for (int h = 0; h < 4; ++h)
#pragma unroll
      for (int c = 0; c < 5; ++c) ob[(h * WOUT + wo) * 5 + c] = acc[h][c];
  }
}

// ---------------- Q/K/V projection (R7-proven fp32, LDS weights) ----------
// Qb/Kb: [b][s][32] bf16, d 20..31 ZERO (K-dim padding must be zero).
// Vt:    [b][32][1024] bf16, d-major. Q folded scale 1/sqrt(20).
__global__ __launch_bounds__(256) void proj_kernel(
    const float* __restrict__ X,
    const float* __restrict__ Kw, const float* __restrict__ Qw,
    const float* __restrict__ Vw,
    ushort_t* __restrict__ Qb, ushort_t* __restrict__ Kb,
    ushort_t* __restrict__ Vt) {
  __shared__ float kw[400], qw[400], vw[400];
  for (int j = threadIdx.x; j < 400; j += 256) {
    kw[j] = Kw[j]; qw[j] = Qw[j]; vw[j] = Vw[j];
  }
  __syncthreads();
  int r = blockIdx.x * 256 + threadIdx.x;   // row in [0, 65536)
  const float4* xr4 = (const float4*)(X + (size_t)r * D_);
  float x[D_];
#pragma unroll
  for (int i = 0; i < 5; ++i) {
    float4 t = xr4[i];
    x[4*i] = t.x; x[4*i+1] = t.y; x[4*i+2] = t.z; x[4*i+3] = t.w;
  }
  float q[D_], k[D_], v[D_];
#pragma unroll
  for (int j = 0; j < D_; ++j) { q[j] = 0.f; k[j] = 0.f; v[j] = 0.f; }
#pragma unroll
  for (int i = 0; i < D_; ++i) {
#pragma unroll
    for (int j = 0; j < D_; ++j) {
      q[j] += x[i] * qw[i * D_ + j];
      k[j] += x[i] * kw[i * D_ + j];
      v[j] += x[i] * vw[i * D_ + j];
    }
  }
  const float sc = 0.22360679774997896f;  // 1/sqrt(20)
  ushort_t qt[32], kt[32];
#pragma unroll
  for (int j = 0; j < D_; ++j) { qt[j] = f2bf(q[j] * sc); kt[j] = f2bf(k[j]); }
#pragma unroll
  for (int j = D_; j < 32; ++j) { qt[j] = 0; kt[j] = 0; }
  int4* qd = (int4*)(Qb + (size_t)r * 32);
  int4* kd = (int4*)(Kb + (size_t)r * 32);
#pragma unroll
  for (int j = 0; j < 4; ++j) {
    qd[j] = *(const int4*)(qt + 8 * j);
    kd[j] = *(const int4*)(kt + 8 * j);
  }
  const int bb = r >> 10, ss = r & 1023;
  ushort_t* vbase = Vt + ((size_t)bb * 32) * 1024 + ss;
#pragma unroll
  for (int d = 0; d < D_; ++d) vbase[d * 1024] = f2bf(v[d]);  // coalesced across lanes
}

// ---------------- causal attention via bf16 MFMA ----------------
// 16 strips of 64 q-rows per batch. Strip swizzle: co-resident blocks are
// stride-256 apart, so strip = (bx + 4*(by>>4)) & 15 gives each CU strips
// {c,c+4,c+8,c+12} (CU load 28..40 tile-units -> makespan 1.18x not 1.9x).
// Wave w owns rows qbase=q0+16w..+15 (A-frag: row=lane&15, k=quad*8+j).
// Per 128-t staged tile: 4 chunks of 32 t. Chunk: 2 QK MFMAs (t-halves),
// exp+mask on C-frags (row=quad*4+reg, col=lane&15), P->LDS->A-frag
// round-trip (wave-synchronous, lgkmcnt fence), 2 PV MFMAs. l accumulated
// from bf16-rounded P so normalization cancels rounding. No max-subtraction
// needed (|s|<<1). O in fp32 C-frags.
#define TT_ 128
__global__ __launch_bounds__(256) void attn_kernel(
    const ushort_t* __restrict__ Qb, const ushort_t* __restrict__ Kb,
    const ushort_t* __restrict__ Vt, float* __restrict__ out) {
  const int b     = blockIdx.y;
  const int strip = (blockIdx.x + 4 * (blockIdx.y >> 4)) & 15;
  const int q0    = strip * 64;
  const int tid   = threadIdx.x;
  const int w     = tid >> 6;             // wave 0..3
  const int lane  = tid & 63;
  const int n     = lane & 15;
  const int quad  = lane >> 4;
  const int qbase = q0 + 16 * w;
  __shared__ ushort_t kts[128 * 40];      // K tile, row stride 40 us (80 B)
  __shared__ ushort_t vts[32 * 136];      // V^T tile, row stride 136 us (272 B)
  __shared__ ushort_t pts[4][16 * 40];    // per-wave P scratch, stride 40 us
  const ushort_t* KbB = Kb + (size_t)b * 1024 * 32;
  const ushort_t* VtB = Vt + (size_t)b * 32 * 1024;
  short8_t qfrag = *(const short8_t*)(Qb + ((size_t)(b * 1024 + qbase + n)) * 32 + quad * 8);
  f32x4_t oA = {0.f, 0.f, 0.f, 0.f};
  f32x4_t oB = {0.f, 0.f, 0.f, 0.f};
  f32x4_t lac = {0.f, 0.f, 0.f, 0.f};
  const f32x4_t zero = {0.f, 0.f, 0.f, 0.f};
  const int Tw = qbase + 16;              // exclusive t bound for this wave
  const int nt = q0 + 64;                 // block-uniform staging bound
  ushort_t* prow = pts[w];
  for (int t0 = 0; t0 < nt; t0 += TT_) {
    __syncthreads();
    for (int i = tid; i < 512; i += 256) {
      int row = i >> 2, qc = i & 3;
      *(int4*)(kts + row * 40 + qc * 8) =
          *(const int4*)(KbB + (size_t)(t0 + row) * 32 + qc * 8);
    }
    for (int i = tid; i < 320; i += 256) {
      int row = i >> 4, cc = i & 15;
      *(int4*)(vts + row * 136 + cc * 8) =
          *(const int4*)(VtB + (size_t)row * 1024 + t0 + cc * 8);
    }
    __syncthreads();
#pragma unroll 1
    for (int cc = 0; cc < 4; ++cc) {
      const int tc = t0 + cc * 32;
      if (tc >= Tw) break;                // wave-uniform
      const short8_t kfA = *(const short8_t*)(kts + (cc * 32 + n) * 40 + quad * 8);
      const short8_t kfB = *(const short8_t*)(kts + (cc * 32 + 16 + n) * 40 + quad * 8);
      f32x4_t sA = __builtin_amdgcn_mfma_f32_16x16x32_bf16(qfrag, kfA, zero, 0, 0, 0);
      f32x4_t sB = __builtin_amdgcn_mfma_f32_16x16x32_bf16(qfrag, kfB, zero, 0, 0, 0);
#pragma unroll
      for (int r = 0; r < 4; ++r) {
        const int qg = qbase + quad * 4 + r;
        float pA = (tc + n      <= qg) ? __expf(sA[r]) : 0.f;
        float pB = (tc + 16 + n <= qg) ? __expf(sB[r]) : 0.f;
        ushort_t hA = f2bf(pA), hB = f2bf(pB);
        lac[r] += bf2f(hA) + bf2f(hB);    // consistent with bf16 P used in PV
        prow[(quad * 4 + r) * 40 + n]      = hA;
        prow[(quad * 4 + r) * 40 + 16 + n] = hB;
      }
      __asm__ volatile("s_waitcnt lgkmcnt(0)" ::: "memory");  // wave-sync LDS RAW
      short8_t pfrag = *(const short8_t*)(prow + n * 40 + quad * 8);
      const short8_t vfA = *(const short8_t*)(vts + n * 136 + cc * 32 + quad * 8);
      const short8_t vfB = *(const short8_t*)(vts + (16 + n) * 136 + cc * 32 + quad * 8);
      oA = __builtin_amdgcn_mfma_f32_16x16x32_bf16(pfrag, vfA, oA, 0, 0, 0);
      oB = __builtin_amdgcn_mfma_f32_16x16x32_bf16(pfrag, vfB, oB, 0, 0, 0);
    }
  }
#pragma unroll
  for (int m = 1; m <= 8; m <<= 1) {
#pragma unroll
    for (int r = 0; r < 4; ++r) lac[r] += __shfl_xor(lac[r], m, 64);
  }
  float* ob = out + ((size_t)(b * 1024 + qbase)) * 20;
#pragma unroll
  for (int r = 0; r < 4; ++r) {
    const float inv = 1.f / lac[r];
    const int qq = quad * 4 + r;
    ob[qq * 20 + n] = oA[r] * inv;                    // d = 0..15
    if (n < 4) ob[qq * 20 + 16 + n] = oB[r] * inv;    // d = 16..19
  }
}

// ---------------- W1 transpose (once per call) ----------------
__global__ __launch_bounds__(256) void transpose_w1(
    const float* __restrict__ W1,   // [20480, 10]
    float* __restrict__ W1T) {      // [10, 20480]
  int idx = blockIdx.x * 256 + threadIdx.x;        // 204800 total
  int j = idx / 20480;
  int i = idx % 20480;
  W1T[idx] = W1[i * 10 + j];
}

// ---------------- dense head: stage 1 (partials, vectorized) ----------------
__global__ __launch_bounds__(256) void dense1_partial(
    const float* __restrict__ X,    // [64, 20480]
    const float* __restrict__ W1T,  // [10, 20480]
    float* __restrict__ part) {     // [64, 4, 10]
  const int b = blockIdx.x;
  const int s = blockIdx.y;
  const float4* xb = (const float4*)(X + (size_t)b * 20480 + s * 5120);
  float acc[10];
#pragma unroll
  for (int j = 0; j < 10; ++j) acc[j] = 0.f;
  for (int i = threadIdx.x; i < 1280; i += 256) {
    float4 xv = xb[i];
#pragma unroll
    for (int j = 0; j < 10; ++j) {
      float4 wv = ((const float4*)(W1T + (size_t)j * 20480 + s * 5120))[i];
      acc[j] += xv.x * wv.x + xv.y * wv.y + xv.z * wv.z + xv.w * wv.w;
    }
  }
  __shared__ float red[256][10];
#pragma unroll
  for (int j = 0; j < 10; ++j) red[threadIdx.x][j] = acc[j];
  __syncthreads();
  for (int off = 128; off > 0; off >>= 1) {
    if (threadIdx.x < (unsigned)off) {
#pragma unroll
      for (int j = 0; j < 10; ++j) red[threadIdx.x][j] += red[threadIdx.x + off][j];
    }
    __syncthreads();
  }
  if (threadIdx.x < 10) part[(b * 4 + s) * 10 + threadIdx.x] = red[0][threadIdx.x];
}

// ---------------- dense head: stage 2 (combine + dense2/3) ----------------
__global__ __launch_bounds__(64) void dense_final(
    const float* __restrict__ part,
    const float* __restrict__ B1,
    const float* __restrict__ W2, const float* __restrict__ B2,
    const float* __restrict__ W3, const float* __restrict__ B3,
    float* __restrict__ out) {
  const int b = blockIdx.x;
  __shared__ float y1[10], y2[10];
  if (threadIdx.x < 10) {
    int j = threadIdx.x;
    y1[j] = part[(b*4+0)*10 + j] + part[(b*4+1)*10 + j] +
            part[(b*4+2)*10 + j] + part[(b*4+3)*10 + j] + B1[j];
  }
  __syncthreads();
  if (threadIdx.x < 10) {
    int j = threadIdx.x;
    float s = B2[j];
#pragma unroll
    for (int i = 0; i < 10; ++i) s += y1[i] * W2[i * 10 + j];
    y2[j] = s;
  }
  __syncthreads();
  if (threadIdx.x < 10) {
    int j = threadIdx.x;
    float s = B3[j];
#pragma unroll
    for (int i = 0; i < 10; ++i) s += y2[i] * W3[i * 10 + j];
    out[b * 10 + j] = s;
  }
}

extern "C" void kernel_launch(void* const* d_in, const int* in_sizes, int n_in,
                              void* d_out, int out_size, void* d_ws, size_t ws_size,
                              hipStream_t stream) {
  const int*   inp = (const int*)d_in[0];
  const float* cw1 = (const float*)d_in[1];
  const float* cb1 = (const float*)d_in[2];
  const float* cw2 = (const float*)d_in[3];
  const float* cb2 = (const float*)d_in[4];
  const float* cw3 = (const float*)d_in[5];
  const float* cb3 = (const float*)d_in[6];
  const float* a1K = (const float*)d_in[7];
  const float* a1Q = (const float*)d_in[8];
  const float* a1V = (const float*)d_in[9];
  const float* a2K = (const float*)d_in[10];
  const float* a2Q = (const float*)d_in[11];
  const float* a2V = (const float*)d_in[12];
  const float* a3K = (const float*)d_in[13];
  const float* a3Q = (const float*)d_in[14];
  const float* a3V = (const float*)d_in[15];
  const float* dw1 = (const float*)d_in[16];
  const float* db1 = (const float*)d_in[17];
  const float* dw2 = (const float*)d_in[18];
  const float* db2 = (const float*)d_in[19];
  const float* dw3 = (const float*)d_in[20];
  const float* db3 = (const float*)d_in[21];
  float* outp = (float*)d_out;

  // workspace layout (float units)
  float* wsf = (float*)d_ws;
  float*    c1   = wsf;                         // [B,4,4096,5]   [0 .. 5,242,880)
  float*    c2   = wsf + 5242880;               // [B,4,2048,5]   [5,242,880 .. 7,864,320)
  float*    x    = wsf + 7864320;               // [B,S,20]       [7,864,320 .. 9,175,040)
  ushort_t* qb   = (ushort_t*)(wsf);            // [B,S,32] bf16  [0 .. 1,048,576) fl
  ushort_t* kb   = (ushort_t*)(wsf + 1048576);  //                [1,048,576 .. 2,097,152)
  ushort_t* vt   = (ushort_t*)(wsf + 2097152);  // [B,32,S] bf16  [2,097,152 .. 3,145,728)
  float*    o    = wsf + 3145728;               // [B,S,20]       [3,145,728 .. 4,456,448)
  float*    part = wsf + 4456448;               // [64,4,10]      2,560 floats
  float*    w1t  = wsf + 4459008;               // [10, 20480]    204,800 floats

  conv1_kernel<<<1024, 256, 0, stream>>>(inp, cw1, cb1, c1);
  conv5_kernel<4096, false><<<dim3(8, 64), 256, 0, stream>>>(c1, cw2, cb2, c2);
  conv5_kernel<2048, true><<<dim3(4, 64), 256, 0, stream>>>(c2, cw3, cb3, x);
  // c1 dead from here; qb/kb/vt/o live in its footprint.
  transpose_w1<<<800, 256, 0, stream>>>(dw1, w1t);

  proj_kernel<<<256, 256, 0, stream>>>(x, a1K, a1Q, a1V, qb, kb, vt);
  attn_kernel<<<dim3(16, 64), 256, 0, stream>>>(qb, kb, vt, o);

  proj_kernel<<<256, 256, 0, stream>>>(o, a2K, a2Q, a2V, qb, kb, vt);
  attn_kernel<<<dim3(16, 64), 256, 0, stream>>>(qb, kb, vt, x);

  proj_kernel<<<256, 256, 0, stream>>>(x, a3K, a3Q, a3V, qb, kb, vt);
  attn_kernel<<<dim3(16, 64), 256, 0, stream>>>(qb, kb, vt, o);

  dense1_partial<<<dim3(64, 4), 256, 0, stream>>>(o, w1t, part);
  dense_final<<<64, 64, 0, stream>>>(part, db1, dw2, db2, dw3, db3, outp);
}

// Round 11
// 264.655 us; speedup vs baseline: 1.1214x; 1.1161x over previous
//
#include <hip/hip_runtime.h>
#include <hip/hip_bf16.h>

// Model: one_hot -> 3x Conv2D(5,(4,4),(1,2),SAME) -> [B,S=1024,D=20]
//        -> 3x causal self-attention -> flatten -> 3x Dense(10)
// B=64, L=8192, S=1024, D=20.
// Attention uses bf16 MFMA (16x16x32, D padded to K=32). Scores |s|<<1 ->
// streaming softmax needs no max-subtraction (exact fp32 C-frag accumulation).
// Convs/proj/dense fp32.
// R11: conv5 reverted to R7-proven per-thread version. The R9 LDS-slab's
// rolled load->ds_write staging loop serialized on vmcnt(0) per iteration
// (~40 global round-trips/thread) and cost +31 us — independent register
// loads hide latency; a rolled global->LDS copy does not.

#define B_ 64
#define L_ 8192
#define S_ 1024
#define D_ 20

typedef unsigned short ushort_t;
typedef __attribute__((ext_vector_type(8))) short short8_t;  // 8 bf16 (4 VGPRs)
typedef __attribute__((ext_vector_type(4))) float f32x4_t;   // MFMA C/D

__device__ __forceinline__ ushort_t f2bf(float f) {          // RNE fp32->bf16
  unsigned u = __float_as_uint(f);
  return (ushort_t)((u + 0x7fffu + ((u >> 16) & 1u)) >> 16);
}
__device__ __forceinline__ float bf2f(ushort_t h) {
  return __uint_as_float(((unsigned)h) << 16);
}

// ---------------- conv1: one-hot input, CI=1 ----------------
__global__ __launch_bounds__(256) void conv1_kernel(
    const int* __restrict__ inp, const float* __restrict__ W,
    const float* __restrict__ Bi, float* __restrict__ out) {
  __shared__ float ws[80];
  __shared__ float bs[5];
  if (threadIdx.x < 80) ws[threadIdx.x] = W[threadIdx.x];
  if (threadIdx.x < 5)  bs[threadIdx.x] = Bi[threadIdx.x];
  __syncthreads();
  int idx = blockIdx.x * 256 + threadIdx.x;   // (b, wo), wo in [0,4096)
  int b  = idx >> 12;
  int wo = idx & 4095;
  float acc[4][5];
#pragma unroll
  for (int h = 0; h < 4; ++h)
#pragma unroll
    for (int c = 0; c < 5; ++c) acc[h][c] = bs[c];
  const int* ib = inp + (size_t)b * L_;
#pragma unroll
  for (int kw = 0; kw < 4; ++kw) {
    int wi = 2 * wo - 1 + kw;
    if (wi >= 0 && wi < L_) {
      int v = ib[wi];
#pragma unroll
      for (int h = 0; h < 4; ++h) {
        int kh = v - h + 1;
        if (kh >= 0 && kh < 4) {
#pragma unroll
          for (int c = 0; c < 5; ++c) acc[h][c] += ws[(kh * 4 + kw) * 5 + c];
        }
      }
    }
  }
  float* ob = out + (size_t)b * 4 * 4096 * 5;
#pragma unroll
  for (int h = 0; h < 4; ++h)
#pragma unroll
    for (int c = 0; c < 5; ++c) ob[(h * 4096 + wo) * 5 + c] = acc[h][c];
}

// ---------------- conv2/conv3: CI=5, CO=5 (R7-proven per-thread version) ----
// 80 independent scalar global loads per thread (compiler keeps many
// outstanding) + LDS-broadcast weights.
template <int WIN, bool TRANS>
__global__ __launch_bounds__(256) void conv5_kernel(
    const float* __restrict__ in, const float* __restrict__ W,
    const float* __restrict__ Bi, float* __restrict__ out) {
  constexpr int WOUT = WIN / 2;
  __shared__ float ws[400];
  __shared__ float bs[5];
  for (int j = threadIdx.x; j < 400; j += 256) ws[j] = W[j];
  if (threadIdx.x < 5) bs[threadIdx.x] = Bi[threadIdx.x];
  __syncthreads();
  int idx = blockIdx.x * 256 + threadIdx.x;   // (b, wo)
  int b  = idx / WOUT;
  int wo = idx % WOUT;
  float val[4][4][5];
#pragma unroll
  for (int hi = 0; hi < 4; ++hi) {
    const float* ir = in + ((size_t)b * 4 + hi) * WIN * 5;
#pragma unroll
    for (int kw = 0; kw < 4; ++kw) {
      int wi = 2 * wo - 1 + kw;
      bool ok = (wi >= 0 && wi < WIN);
#pragma unroll
      for (int ci = 0; ci < 5; ++ci) val[hi][kw][ci] = ok ? ir[wi * 5 + ci] : 0.f;
    }
  }
  float acc[4][5];
#pragma unroll
  for (int h = 0; h < 4; ++h)
#pragma unroll
    for (int c = 0; c < 5; ++c) acc[h][c] = bs[c];
#pragma unroll
  for (int kh = 0; kh < 4; ++kh)
#pragma unroll
    for (int kw = 0; kw < 4; ++kw)
#pragma unroll
      for (int ci = 0; ci < 5; ++ci) {
        const float* wp = ws + ((kh * 4 + kw) * 5 + ci) * 5;
        float w0 = wp[0], w1 = wp[1], w2 = wp[2], w3 = wp[3], w4 = wp[4];
#pragma unroll
        for (int h = 0; h < 4; ++h) {
          int hi = h - 1 + kh;
          if (hi >= 0 && hi < 4) {
            float x = val[hi][kw][ci];
            acc[h][0] += w0 * x; acc[h][1] += w1 * x; acc[h][2] += w2 * x;
            acc[h][3] += w3 * x; acc[h][4] += w4 * x;
          }
        }
      }
  if (TRANS) {
    float* ob = out + ((size_t)b * WOUT + wo) * 20;
#pragma unroll
    for (int h = 0; h < 4; ++h)
#pragma unroll
      for (int c = 0; c < 5; ++c) ob[h * 5 + c] = acc[h][c];
  } else {
    float* ob = out + (size_t)b * 4 * WOUT * 5;
#pragma unroll
    for (int h = 0; h < 4; ++h)
#pragma unroll
      for (int c = 0; c < 5; ++c) ob[(h * WOUT + wo) * 5 + c] = acc[h][c];
  }
}

// ---------------- Q/K/V projection (R7-proven fp32, LDS weights) ----------
// Qb/Kb: [b][s][32] bf16, d 20..31 ZERO (K-dim padding must be zero).
// Vt:    [b][32][1024] bf16, d-major. Q folded scale 1/sqrt(20).
__global__ __launch_bounds__(256) void proj_kernel(
    const float* __restrict__ X,
    const float* __restrict__ Kw, const float* __restrict__ Qw,
    const float* __restrict__ Vw,
    ushort_t* __restrict__ Qb, ushort_t* __restrict__ Kb,
    ushort_t* __restrict__ Vt) {
  __shared__ float kw[400], qw[400], vw[400];
  for (int j = threadIdx.x; j < 400; j += 256) {
    kw[j] = Kw[j]; qw[j] = Qw[j]; vw[j] = Vw[j];
  }
  __syncthreads();
  int r = blockIdx.x * 256 + threadIdx.x;   // row in [0, 65536)
  const float4* xr4 = (const float4*)(X + (size_t)r * D_);
  float x[D_];
#pragma unroll
  for (int i = 0; i < 5; ++i) {
    float4 t = xr4[i];
    x[4*i] = t.x; x[4*i+1] = t.y; x[4*i+2] = t.z; x[4*i+3] = t.w;
  }
  float q[D_], k[D_], v[D_];
#pragma unroll
  for (int j = 0; j < D_; ++j) { q[j] = 0.f; k[j] = 0.f; v[j] = 0.f; }
#pragma unroll
  for (int i = 0; i < D_; ++i) {
#pragma unroll
    for (int j = 0; j < D_; ++j) {
      q[j] += x[i] * qw[i * D_ + j];
      k[j] += x[i] * kw[i * D_ + j];
      v[j] += x[i] * vw[i * D_ + j];
    }
  }
  const float sc = 0.22360679774997896f;  // 1/sqrt(20)
  ushort_t qt[32], kt[32];
#pragma unroll
  for (int j = 0; j < D_; ++j) { qt[j] = f2bf(q[j] * sc); kt[j] = f2bf(k[j]); }
#pragma unroll
  for (int j = D_; j < 32; ++j) { qt[j] = 0; kt[j] = 0; }
  int4* qd = (int4*)(Qb + (size_t)r * 32);
  int4* kd = (int4*)(Kb + (size_t)r * 32);
#pragma unroll
  for (int j = 0; j < 4; ++j) {
    qd[j] = *(const int4*)(qt + 8 * j);
    kd[j] = *(const int4*)(kt + 8 * j);
  }
  const int bb = r >> 10, ss = r & 1023;
  ushort_t* vbase = Vt + ((size_t)bb * 32) * 1024 + ss;
#pragma unroll
  for (int d = 0; d < D_; ++d) vbase[d * 1024] = f2bf(v[d]);  // coalesced across lanes
}

// ---------------- causal attention via bf16 MFMA ----------------
// 16 strips of 64 q-rows per batch. Strip swizzle: co-resident blocks are
// stride-256 apart, so strip = (bx + 4*(by>>4)) & 15 gives each CU strips
// {c,c+4,c+8,c+12} (CU load 28..40 tile-units -> makespan 1.18x not 1.9x).
// Wave w owns rows qbase=q0+16w..+15 (A-frag: row=lane&15, k=quad*8+j).
// Per 128-t staged tile: 4 chunks of 32 t. Chunk: 2 QK MFMAs (t-halves),
// exp+mask on C-frags (row=quad*4+reg, col=lane&15), P->LDS->A-frag
// round-trip (wave-synchronous, lgkmcnt fence), 2 PV MFMAs. l accumulated
// from bf16-rounded P so normalization cancels rounding. No max-subtraction
// needed (|s|<<1). O in fp32 C-frags.
#define TT_ 128
__global__ __launch_bounds__(256) void attn_kernel(
    const ushort_t* __restrict__ Qb, const ushort_t* __restrict__ Kb,
    const ushort_t* __restrict__ Vt, float* __restrict__ out) {
  const int b     = blockIdx.y;
  const int strip = (blockIdx.x + 4 * (blockIdx.y >> 4)) & 15;
  const int q0    = strip * 64;
  const int tid   = threadIdx.x;
  const int w     = tid >> 6;             // wave 0..3
  const int lane  = tid & 63;
  const int n     = lane & 15;
  const int quad  = lane >> 4;
  const int qbase = q0 + 16 * w;
  __shared__ ushort_t kts[128 * 40];      // K tile, row stride 40 us (80 B)
  __shared__ ushort_t vts[32 * 136];      // V^T tile, row stride 136 us (272 B)
  __shared__ ushort_t pts[4][16 * 40];    // per-wave P scratch, stride 40 us
  const ushort_t* KbB = Kb + (size_t)b * 1024 * 32;
  const ushort_t* VtB = Vt + (size_t)b * 32 * 1024;
  short8_t qfrag = *(const short8_t*)(Qb + ((size_t)(b * 1024 + qbase + n)) * 32 + quad * 8);
  f32x4_t oA = {0.f, 0.f, 0.f, 0.f};
  f32x4_t oB = {0.f, 0.f, 0.f, 0.f};
  f32x4_t lac = {0.f, 0.f, 0.f, 0.f};
  const f32x4_t zero = {0.f, 0.f, 0.f, 0.f};
  const int Tw = qbase + 16;              // exclusive t bound for this wave
  const int nt = q0 + 64;                 // block-uniform staging bound
  ushort_t* prow = pts[w];
  for (int t0 = 0; t0 < nt; t0 += TT_) {
    __syncthreads();
    for (int i = tid; i < 512; i += 256) {
      int row = i >> 2, qc = i & 3;
      *(int4*)(kts + row * 40 + qc * 8) =
          *(const int4*)(KbB + (size_t)(t0 + row) * 32 + qc * 8);
    }
    for (int i = tid; i < 320; i += 256) {
      int row = i >> 4, cc = i & 15;
      *(int4*)(vts + row * 136 + cc * 8) =
          *(const int4*)(VtB + (size_t)row * 1024 + t0 + cc * 8);
    }
    __syncthreads();
#pragma unroll 1
    for (int cc = 0; cc < 4; ++cc) {
      const int tc = t0 + cc * 32;
      if (tc >= Tw) break;                // wave-uniform
      const short8_t kfA = *(const short8_t*)(kts + (cc * 32 + n) * 40 + quad * 8);
      const short8_t kfB = *(const short8_t*)(kts + (cc * 32 + 16 + n) * 40 + quad * 8);
      f32x4_t sA = __builtin_amdgcn_mfma_f32_16x16x32_bf16(qfrag, kfA, zero, 0, 0, 0);
      f32x4_t sB = __builtin_amdgcn_mfma_f32_16x16x32_bf16(qfrag, kfB, zero, 0, 0, 0);
#pragma unroll
      for (int r = 0; r < 4; ++r) {
        const int qg = qbase + quad * 4 + r;
        float pA = (tc + n      <= qg) ? __expf(sA[r]) : 0.f;
        float pB = (tc + 16 + n <= qg) ? __expf(sB[r]) : 0.f;
        ushort_t hA = f2bf(pA), hB = f2bf(pB);
        lac[r] += bf2f(hA) + bf2f(hB);    // consistent with bf16 P used in PV
        prow[(quad * 4 + r) * 40 + n]      = hA;
        prow[(quad * 4 + r) * 40 + 16 + n] = hB;
      }
      __asm__ volatile("s_waitcnt lgkmcnt(0)" ::: "memory");  // wave-sync LDS RAW
      short8_t pfrag = *(const short8_t*)(prow + n * 40 + quad * 8);
      const short8_t vfA = *(const short8_t*)(vts + n * 136 + cc * 32 + quad * 8);
      const short8_t vfB = *(const short8_t*)(vts + (16 + n) * 136 + cc * 32 + quad * 8);
      oA = __builtin_amdgcn_mfma_f32_16x16x32_bf16(pfrag, vfA, oA, 0, 0, 0);
      oB = __builtin_amdgcn_mfma_f32_16x16x32_bf16(pfrag, vfB, oB, 0, 0, 0);
    }
  }
#pragma unroll
  for (int m = 1; m <= 8; m <<= 1) {
#pragma unroll
    for (int r = 0; r < 4; ++r) lac[r] += __shfl_xor(lac[r], m, 64);
  }
  float* ob = out + ((size_t)(b * 1024 + qbase)) * 20;
#pragma unroll
  for (int r = 0; r < 4; ++r) {
    const float inv = 1.f / lac[r];
    const int qq = quad * 4 + r;
    ob[qq * 20 + n] = oA[r] * inv;                    // d = 0..15
    if (n < 4) ob[qq * 20 + 16 + n] = oB[r] * inv;    // d = 16..19
  }
}

// ---------------- W1 transpose (once per call) ----------------
__global__ __launch_bounds__(256) void transpose_w1(
    const float* __restrict__ W1,   // [20480, 10]
    float* __restrict__ W1T) {      // [10, 20480]
  int idx = blockIdx.x * 256 + threadIdx.x;        // 204800 total
  int j = idx / 20480;
  int i = idx % 20480;
  W1T[idx] = W1[i * 10 + j];
}

// ---------------- dense head: stage 1 (partials, vectorized) ----------------
__global__ __launch_bounds__(256) void dense1_partial(
    const float* __restrict__ X,    // [64, 20480]
    const float* __restrict__ W1T,  // [10, 20480]
    float* __restrict__ part) {     // [64, 4, 10]
  const int b = blockIdx.x;
  const int s = blockIdx.y;
  const float4* xb = (const float4*)(X + (size_t)b * 20480 + s * 5120);
  float acc[10];
#pragma unroll
  for (int j = 0; j < 10; ++j) acc[j] = 0.f;
  for (int i = threadIdx.x; i < 1280; i += 256) {
    float4 xv = xb[i];
#pragma unroll
    for (int j = 0; j < 10; ++j) {
      float4 wv = ((const float4*)(W1T + (size_t)j * 20480 + s * 5120))[i];
      acc[j] += xv.x * wv.x + xv.y * wv.y + xv.z * wv.z + xv.w * wv.w;
    }
  }
  __shared__ float red[256][10];
#pragma unroll
  for (int j = 0; j < 10; ++j) red[threadIdx.x][j] = acc[j];
  __syncthreads();
  for (int off = 128; off > 0; off >>= 1) {
    if (threadIdx.x < (unsigned)off) {
#pragma unroll
      for (int j = 0; j < 10; ++j) red[threadIdx.x][j] += red[threadIdx.x + off][j];
    }
    __syncthreads();
  }
  if (threadIdx.x < 10) part[(b * 4 + s) * 10 + threadIdx.x] = red[0][threadIdx.x];
}

// ---------------- dense head: stage 2 (combine + dense2/3) ----------------
__global__ __launch_bounds__(64) void dense_final(
    const float* __restrict__ part,
    const float* __restrict__ B1,
    const float* __restrict__ W2, const float* __restrict__ B2,
    const float* __restrict__ W3, const float* __restrict__ B3,
    float* __restrict__ out) {
  const int b = blockIdx.x;
  __shared__ float y1[10], y2[10];
  if (threadIdx.x < 10) {
    int j = threadIdx.x;
    y1[j] = part[(b*4+0)*10 + j] + part[(b*4+1)*10 + j] +
            part[(b*4+2)*10 + j] + part[(b*4+3)*10 + j] + B1[j];
  }
  __syncthreads();
  if (threadIdx.x < 10) {
    int j = threadIdx.x;
    float s = B2[j];
#pragma unroll
    for (int i = 0; i < 10; ++i) s += y1[i] * W2[i * 10 + j];
    y2[j] = s;
  }
  __syncthreads();
  if (threadIdx.x < 10) {
    int j = threadIdx.x;
    float s = B3[j];
#pragma unroll
    for (int i = 0; i < 10; ++i) s += y2[i] * W3[i * 10 + j];
    out[b * 10 + j] = s;
  }
}

extern "C" void kernel_launch(void* const* d_in, const int* in_sizes, int n_in,
                              void* d_out, int out_size, void* d_ws, size_t ws_size,
                              hipStream_t stream) {
  const int*   inp = (const int*)d_in[0];
  const float* cw1 = (const float*)d_in[1];
  const float* cb1 = (const float*)d_in[2];
  const float* cw2 = (const float*)d_in[3];
  const float* cb2 = (const float*)d_in[4];
  const float* cw3 = (const float*)d_in[5];
  const float* cb3 = (const float*)d_in[6];
  const float* a1K = (const float*)d_in[7];
  const float* a1Q = (const float*)d_in[8];
  const float* a1V = (const float*)d_in[9];
  const float* a2K = (const float*)d_in[10];
  const float* a2Q = (const float*)d_in[11];
  const float* a2V = (const float*)d_in[12];
  const float* a3K = (const float*)d_in[13];
  const float* a3Q = (const float*)d_in[14];
  const float* a3V = (const float*)d_in[15];
  const float* dw1 = (const float*)d_in[16];
  const float* db1 = (const float*)d_in[17];
  const float* dw2 = (const float*)d_in[18];
  const float* db2 = (const float*)d_in[19];
  const float* dw3 = (const float*)d_in[20];
  const float* db3 = (const float*)d_in[21];
  float* outp = (float*)d_out;

  // workspace layout (float units)
  float* wsf = (float*)d_ws;
  float*    c1   = wsf;                         // [B,4,4096,5]   [0 .. 5,242,880)
  float*    c2   = wsf + 5242880;               // [B,4,2048,5]   [5,242,880 .. 7,864,320)
  float*    x    = wsf + 7864320;               // [B,S,20]       [7,864,320 .. 9,175,040)
  ushort_t* qb   = (ushort_t*)(wsf);            // [B,S,32] bf16  [0 .. 1,048,576) fl
  ushort_t* kb   = (ushort_t*)(wsf + 1048576);  //                [1,048,576 .. 2,097,152)
  ushort_t* vt   = (ushort_t*)(wsf + 2097152);  // [B,32,S] bf16  [2,097,152 .. 3,145,728)
  float*    o    = wsf + 3145728;               // [B,S,20]       [3,145,728 .. 4,456,448)
  float*    part = wsf + 4456448;               // [64,4,10]      2,560 floats
  float*    w1t  = wsf + 4459008;               // [10, 20480]    204,800 floats

  conv1_kernel<<<1024, 256, 0, stream>>>(inp, cw1, cb1, c1);
  conv5_kernel<4096, false><<<512, 256, 0, stream>>>(c1, cw2, cb2, c2);
  conv5_kernel<2048, true><<<256, 256, 0, stream>>>(c2, cw3, cb3, x);
  // c1 dead from here; qb/kb/vt/o live in its footprint.
  transpose_w1<<<800, 256, 0, stream>>>(dw1, w1t);

  proj_kernel<<<256, 256, 0, stream>>>(x, a1K, a1Q, a1V, qb, kb, vt);
  attn_kernel<<<dim3(16, 64), 256, 0, stream>>>(qb, kb, vt, o);

  proj_kernel<<<256, 256, 0, stream>>>(o, a2K, a2Q, a2V, qb, kb, vt);
  attn_kernel<<<dim3(16, 64), 256, 0, stream>>>(qb, kb, vt, x);

  proj_kernel<<<256, 256, 0, stream>>>(x, a3K, a3Q, a3V, qb, kb, vt);
  attn_kernel<<<dim3(16, 64), 256, 0, stream>>>(qb, kb, vt, o);

  dense1_partial<<<dim3(64, 4), 256, 0, stream>>>(o, w1t, part);
  dense_final<<<64, 64, 0, stream>>>(part, db1, dw2, db2, dw3, db3, outp);
}

// Round 12
// 250.395 us; speedup vs baseline: 1.1853x; 1.0570x over previous
//
#include <hip/hip_runtime.h>
#include <hip/hip_bf16.h>

// Model: one_hot -> 3x Conv2D(5,(4,4),(1,2),SAME) -> [B,S=1024,D=20]
//        -> 3x causal self-attention -> flatten -> 3x Dense(10)
// B=64, L=8192, S=1024, D=20.
// Attention uses bf16 MFMA (16x16x32, D padded to K=32). Scores |s|<<1 ->
// streaming softmax needs no max-subtraction (exact fp32 C-frag accumulation).
// Convs/proj/dense fp32.
// R12: conv1 fused into conv2 (conv12_kernel). conv1 is one-hot weight-adds,
// recomputed in registers from 10 int loads/thread (vs 80 scattered float
// loads) — removes the conv1 launch and the 21MB c1 write+read. Accumulation
// order kept bit-identical to the separate kernels.

#define B_ 64
#define L_ 8192
#define S_ 1024
#define D_ 20

typedef unsigned short ushort_t;
typedef __attribute__((ext_vector_type(8))) short short8_t;  // 8 bf16 (4 VGPRs)
typedef __attribute__((ext_vector_type(4))) float f32x4_t;   // MFMA C/D

__device__ __forceinline__ ushort_t f2bf(float f) {          // RNE fp32->bf16
  unsigned u = __float_as_uint(f);
  return (ushort_t)((u + 0x7fffu + ((u >> 16) & 1u)) >> 16);
}
__device__ __forceinline__ float bf2f(ushort_t h) {
  return __uint_as_float(((unsigned)h) << 16);
}

// ---------------- fused conv1+conv2 ----------------
// One thread per conv2 output column (b, wo), wo in [0,2048).
// conv1 values for the 4 needed input positions are recomputed in registers
// from 10 input ints (sentinel -100 for OOB -> no kh matches). Bit-identical
// accumulation order vs the separate conv1/conv5 kernels.
__global__ __launch_bounds__(256) void conv12_kernel(
    const int* __restrict__ inp,
    const float* __restrict__ W1c, const float* __restrict__ B1c,
    const float* __restrict__ W2c, const float* __restrict__ B2c,
    float* __restrict__ out) {    // c2 [B,4,2048,5]
  __shared__ float w1s[80], b1s[5], w2s[400], b2s[5];
  for (int j = threadIdx.x; j < 400; j += 256) w2s[j] = W2c[j];
  if (threadIdx.x < 80)      w1s[threadIdx.x]      = W1c[threadIdx.x];
  else if (threadIdx.x < 85) b1s[threadIdx.x - 80] = B1c[threadIdx.x - 80];
  else if (threadIdx.x < 90) b2s[threadIdx.x - 85] = B2c[threadIdx.x - 85];
  __syncthreads();
  const int idx = blockIdx.x * 256 + threadIdx.x;  // 131072 total
  const int b  = idx >> 11;
  const int wo = idx & 2047;
  const int* ib = inp + (size_t)b * L_;
  int iv[10];
#pragma unroll
  for (int t = 0; t < 10; ++t) {
    int g = 4 * wo - 3 + t;
    iv[t] = (g >= 0 && g < L_) ? ib[g] : -100;   // sentinel: no kh matches
  }
  // conv1 outputs for positions w1 = 2wo-1+pos, pos 0..3
  float val[4][4][5];                            // [hi][pos][ci]
#pragma unroll
  for (int pos = 0; pos < 4; ++pos) {
    const int w1 = 2 * wo - 1 + pos;
    const bool okp = (w1 >= 0 && w1 < 4096);     // conv2 SAME padding -> 0
#pragma unroll
    for (int hi = 0; hi < 4; ++hi)
#pragma unroll
      for (int ci = 0; ci < 5; ++ci) val[hi][pos][ci] = okp ? b1s[ci] : 0.f;
    if (okp) {
#pragma unroll
      for (int kw = 0; kw < 4; ++kw) {
        const int gw = 2 * w1 - 1 + kw;          // == 4wo-3 + 2pos + kw
        if (gw >= 0 && gw < L_) {
          const int v = iv[2 * pos + kw];
#pragma unroll
          for (int hi = 0; hi < 4; ++hi) {
            const int kh = v - hi + 1;
            if (kh >= 0 && kh < 4) {
#pragma unroll
              for (int ci = 0; ci < 5; ++ci)
                val[hi][pos][ci] += w1s[(kh * 4 + kw) * 5 + ci];
            }
          }
        }
      }
    }
  }
  // conv2 (identical structure/order to conv5_kernel)
  float acc[4][5];
#pragma unroll
  for (int h = 0; h < 4; ++h)
#pragma unroll
    for (int c = 0; c < 5; ++c) acc[h][c] = b2s[c];
#pragma unroll
  for (int kh = 0; kh < 4; ++kh)
#pragma unroll
    for (int kw = 0; kw < 4; ++kw)
#pragma unroll
      for (int ci = 0; ci < 5; ++ci) {
        const float* wp = w2s + ((kh * 4 + kw) * 5 + ci) * 5;
        float w0 = wp[0], w1v = wp[1], w2v = wp[2], w3 = wp[3], w4 = wp[4];
#pragma unroll
        for (int h = 0; h < 4; ++h) {
          int hi = h - 1 + kh;
          if (hi >= 0 && hi < 4) {
            float x = val[hi][kw][ci];
            acc[h][0] += w0 * x;  acc[h][1] += w1v * x; acc[h][2] += w2v * x;
            acc[h][3] += w3 * x;  acc[h][4] += w4 * x;
          }
        }
      }
  float* ob = out + (size_t)b * 4 * 2048 * 5;
#pragma unroll
  for (int h = 0; h < 4; ++h)
#pragma unroll
    for (int c = 0; c < 5; ++c) ob[(h * 2048 + wo) * 5 + c] = acc[h][c];
}

// ---------------- conv3: CI=5, CO=5 (R7-proven per-thread version) ----
template <int WIN, bool TRANS>
__global__ __launch_bounds__(256) void conv5_kernel(
    const float* __restrict__ in, const float* __restrict__ W,
    const float* __restrict__ Bi, float* __restrict__ out) {
  constexpr int WOUT = WIN / 2;
  __shared__ float ws[400];
  __shared__ float bs[5];
  for (int j = threadIdx.x; j < 400; j += 256) ws[j] = W[j];
  if (threadIdx.x < 5) bs[threadIdx.x] = Bi[threadIdx.x];
  __syncthreads();
  int idx = blockIdx.x * 256 + threadIdx.x;   // (b, wo)
  int b  = idx / WOUT;
  int wo = idx % WOUT;
  float val[4][4][5];
#pragma unroll
  for (int hi = 0; hi < 4; ++hi) {
    const float* ir = in + ((size_t)b * 4 + hi) * WIN * 5;
#pragma unroll
    for (int kw = 0; kw < 4; ++kw) {
      int wi = 2 * wo - 1 + kw;
      bool ok = (wi >= 0 && wi < WIN);
#pragma unroll
      for (int ci = 0; ci < 5; ++ci) val[hi][kw][ci] = ok ? ir[wi * 5 + ci] : 0.f;
    }
  }
  float acc[4][5];
#pragma unroll
  for (int h = 0; h < 4; ++h)
#pragma unroll
    for (int c = 0; c < 5; ++c) acc[h][c] = bs[c];
#pragma unroll
  for (int kh = 0; kh < 4; ++kh)
#pragma unroll
    for (int kw = 0; kw < 4; ++kw)
#pragma unroll
      for (int ci = 0; ci < 5; ++ci) {
        const float* wp = ws + ((kh * 4 + kw) * 5 + ci) * 5;
        float w0 = wp[0], w1 = wp[1], w2 = wp[2], w3 = wp[3], w4 = wp[4];
#pragma unroll
        for (int h = 0; h < 4; ++h) {
          int hi = h - 1 + kh;
          if (hi >= 0 && hi < 4) {
            float x = val[hi][kw][ci];
            acc[h][0] += w0 * x; acc[h][1] += w1 * x; acc[h][2] += w2 * x;
            acc[h][3] += w3 * x; acc[h][4] += w4 * x;
          }
        }
      }
  if (TRANS) {
    float* ob = out + ((size_t)b * WOUT + wo) * 20;
#pragma unroll
    for (int h = 0; h < 4; ++h)
#pragma unroll
      for (int c = 0; c < 5; ++c) ob[h * 5 + c] = acc[h][c];
  } else {
    float* ob = out + (size_t)b * 4 * WOUT * 5;
#pragma unroll
    for (int h = 0; h < 4; ++h)
#pragma unroll
      for (int c = 0; c < 5; ++c) ob[(h * WOUT + wo) * 5 + c] = acc[h][c];
  }
}

// ---------------- Q/K/V projection (R7-proven fp32, LDS weights) ----------
// Qb/Kb: [b][s][32] bf16, d 20..31 ZERO (K-dim padding must be zero).
// Vt:    [b][32][1024] bf16, d-major. Q folded scale 1/sqrt(20).
__global__ __launch_bounds__(256) void proj_kernel(
    const float* __restrict__ X,
    const float* __restrict__ Kw, const float* __restrict__ Qw,
    const float* __restrict__ Vw,
    ushort_t* __restrict__ Qb, ushort_t* __restrict__ Kb,
    ushort_t* __restrict__ Vt) {
  __shared__ float kw[400], qw[400], vw[400];
  for (int j = threadIdx.x; j < 400; j += 256) {
    kw[j] = Kw[j]; qw[j] = Qw[j]; vw[j] = Vw[j];
  }
  __syncthreads();
  int r = blockIdx.x * 256 + threadIdx.x;   // row in [0, 65536)
  const float4* xr4 = (const float4*)(X + (size_t)r * D_);
  float x[D_];
#pragma unroll
  for (int i = 0; i < 5; ++i) {
    float4 t = xr4[i];
    x[4*i] = t.x; x[4*i+1] = t.y; x[4*i+2] = t.z; x[4*i+3] = t.w;
  }
  float q[D_], k[D_], v[D_];
#pragma unroll
  for (int j = 0; j < D_; ++j) { q[j] = 0.f; k[j] = 0.f; v[j] = 0.f; }
#pragma unroll
  for (int i = 0; i < D_; ++i) {
#pragma unroll
    for (int j = 0; j < D_; ++j) {
      q[j] += x[i] * qw[i * D_ + j];
      k[j] += x[i] * kw[i * D_ + j];
      v[j] += x[i] * vw[i * D_ + j];
    }
  }
  const float sc = 0.22360679774997896f;  // 1/sqrt(20)
  ushort_t qt[32], kt[32];
#pragma unroll
  for (int j = 0; j < D_; ++j) { qt[j] = f2bf(q[j] * sc); kt[j] = f2bf(k[j]); }
#pragma unroll
  for (int j = D_; j < 32; ++j) { qt[j] = 0; kt[j] = 0; }
  int4* qd = (int4*)(Qb + (size_t)r * 32);
  int4* kd = (int4*)(Kb + (size_t)r * 32);
#pragma unroll
  for (int j = 0; j < 4; ++j) {
    qd[j] = *(const int4*)(qt + 8 * j);
    kd[j] = *(const int4*)(kt + 8 * j);
  }
  const int bb = r >> 10, ss = r & 1023;
  ushort_t* vbase = Vt + ((size_t)bb * 32) * 1024 + ss;
#pragma unroll
  for (int d = 0; d < D_; ++d) vbase[d * 1024] = f2bf(v[d]);  // coalesced across lanes
}

// ---------------- causal attention via bf16 MFMA ----------------
// 16 strips of 64 q-rows per batch. Strip swizzle: co-resident blocks are
// stride-256 apart, so strip = (bx + 4*(by>>4)) & 15 gives each CU strips
// {c,c+4,c+8,c+12} (CU load 28..40 tile-units -> makespan 1.18x not 1.9x).
// Wave w owns rows qbase=q0+16w..+15 (A-frag: row=lane&15, k=quad*8+j).
// Per 128-t staged tile: 4 chunks of 32 t. Chunk: 2 QK MFMAs (t-halves),
// exp+mask on C-frags (row=quad*4+reg, col=lane&15), P->LDS->A-frag
// round-trip (wave-synchronous, lgkmcnt fence), 2 PV MFMAs. l accumulated
// from bf16-rounded P so normalization cancels rounding. No max-subtraction
// needed (|s|<<1). O in fp32 C-frags.
#define TT_ 128
__global__ __launch_bounds__(256) void attn_kernel(
    const ushort_t* __restrict__ Qb, const ushort_t* __restrict__ Kb,
    const ushort_t* __restrict__ Vt, float* __restrict__ out) {
  const int b     = blockIdx.y;
  const int strip = (blockIdx.x + 4 * (blockIdx.y >> 4)) & 15;
  const int q0    = strip * 64;
  const int tid   = threadIdx.x;
  const int w     = tid >> 6;             // wave 0..3
  const int lane  = tid & 63;
  const int n     = lane & 15;
  const int quad  = lane >> 4;
  const int qbase = q0 + 16 * w;
  __shared__ ushort_t kts[128 * 40];      // K tile, row stride 40 us (80 B)
  __shared__ ushort_t vts[32 * 136];      // V^T tile, row stride 136 us (272 B)
  __shared__ ushort_t pts[4][16 * 40];    // per-wave P scratch, stride 40 us
  const ushort_t* KbB = Kb + (size_t)b * 1024 * 32;
  const ushort_t* VtB = Vt + (size_t)b * 32 * 1024;
  short8_t qfrag = *(const short8_t*)(Qb + ((size_t)(b * 1024 + qbase + n)) * 32 + quad * 8);
  f32x4_t oA = {0.f, 0.f, 0.f, 0.f};
  f32x4_t oB = {0.f, 0.f, 0.f, 0.f};
  f32x4_t lac = {0.f, 0.f, 0.f, 0.f};
  const f32x4_t zero = {0.f, 0.f, 0.f, 0.f};
  const int Tw = qbase + 16;              // exclusive t bound for this wave
  const int nt = q0 + 64;                 // block-uniform staging bound
  ushort_t* prow = pts[w];
  for (int t0 = 0; t0 < nt; t0 += TT_) {
    __syncthreads();
    for (int i = tid; i < 512; i += 256) {
      int row = i >> 2, qc = i & 3;
      *(int4*)(kts + row * 40 + qc * 8) =
          *(const int4*)(KbB + (size_t)(t0 + row) * 32 + qc * 8);
    }
    for (int i = tid; i < 320; i += 256) {
      int row = i >> 4, cc = i & 15;
      *(int4*)(vts + row * 136 + cc * 8) =
          *(const int4*)(VtB + (size_t)row * 1024 + t0 + cc * 8);
    }
    __syncthreads();
#pragma unroll 1
    for (int cc = 0; cc < 4; ++cc) {
      const int tc = t0 + cc * 32;
      if (tc >= Tw) break;                // wave-uniform
      const short8_t kfA = *(const short8_t*)(kts + (cc * 32 + n) * 40 + quad * 8);
      const short8_t kfB = *(const short8_t*)(kts + (cc * 32 + 16 + n) * 40 + quad * 8);
      f32x4_t sA = __builtin_amdgcn_mfma_f32_16x16x32_bf16(qfrag, kfA, zero, 0, 0, 0);
      f32x4_t sB = __builtin_amdgcn_mfma_f32_16x16x32_bf16(qfrag, kfB, zero, 0, 0, 0);
#pragma unroll
      for (int r = 0; r < 4; ++r) {
        const int qg = qbase + quad * 4 + r;
        float pA = (tc + n      <= qg) ? __expf(sA[r]) : 0.f;
        float pB = (tc + 16 + n <= qg) ? __expf(sB[r]) : 0.f;
        ushort_t hA = f2bf(pA), hB = f2bf(pB);
        lac[r] += bf2f(hA) + bf2f(hB);    // consistent with bf16 P used in PV
        prow[(quad * 4 + r) * 40 + n]      = hA;
        prow[(quad * 4 + r) * 40 + 16 + n] = hB;
      }
      __asm__ volatile("s_waitcnt lgkmcnt(0)" ::: "memory");  // wave-sync LDS RAW
      short8_t pfrag = *(const short8_t*)(prow + n * 40 + quad * 8);
      const short8_t vfA = *(const short8_t*)(vts + n * 136 + cc * 32 + quad * 8);
      const short8_t vfB = *(const short8_t*)(vts + (16 + n) * 136 + cc * 32 + quad * 8);
      oA = __builtin_amdgcn_mfma_f32_16x16x32_bf16(pfrag, vfA, oA, 0, 0, 0);
      oB = __builtin_amdgcn_mfma_f32_16x16x32_bf16(pfrag, vfB, oB, 0, 0, 0);
    }
  }
#pragma unroll
  for (int m = 1; m <= 8; m <<= 1) {
#pragma unroll
    for (int r = 0; r < 4; ++r) lac[r] += __shfl_xor(lac[r], m, 64);
  }
  float* ob = out + ((size_t)(b * 1024 + qbase)) * 20;
#pragma unroll
  for (int r = 0; r < 4; ++r) {
    const float inv = 1.f / lac[r];
    const int qq = quad * 4 + r;
    ob[qq * 20 + n] = oA[r] * inv;                    // d = 0..15
    if (n < 4) ob[qq * 20 + 16 + n] = oB[r] * inv;    // d = 16..19
  }
}

// ---------------- W1 transpose (once per call) ----------------
__global__ __launch_bounds__(256) void transpose_w1(
    const float* __restrict__ W1,   // [20480, 10]
    float* __restrict__ W1T) {      // [10, 20480]
  int idx = blockIdx.x * 256 + threadIdx.x;        // 204800 total
  int j = idx / 20480;
  int i = idx % 20480;
  W1T[idx] = W1[i * 10 + j];
}

// ---------------- dense head: stage 1 (partials, vectorized) ----------------
__global__ __launch_bounds__(256) void dense1_partial(
    const float* __restrict__ X,    // [64, 20480]
    const float* __restrict__ W1T,  // [10, 20480]
    float* __restrict__ part) {     // [64, 4, 10]
  const int b = blockIdx.x;
  const int s = blockIdx.y;
  const float4* xb = (const float4*)(X + (size_t)b * 20480 + s * 5120);
  float acc[10];
#pragma unroll
  for (int j = 0; j < 10; ++j) acc[j] = 0.f;
  for (int i = threadIdx.x; i < 1280; i += 256) {
    float4 xv = xb[i];
#pragma unroll
    for (int j = 0; j < 10; ++j) {
      float4 wv = ((const float4*)(W1T + (size_t)j * 20480 + s * 5120))[i];
      acc[j] += xv.x * wv.x + xv.y * wv.y + xv.z * wv.z + xv.w * wv.w;
    }
  }
  __shared__ float red[256][10];
#pragma unroll
  for (int j = 0; j < 10; ++j) red[threadIdx.x][j] = acc[j];
  __syncthreads();
  for (int off = 128; off > 0; off >>= 1) {
    if (threadIdx.x < (unsigned)off) {
#pragma unroll
      for (int j = 0; j < 10; ++j) red[threadIdx.x][j] += red[threadIdx.x + off][j];
    }
    __syncthreads();
  }
  if (threadIdx.x < 10) part[(b * 4 + s) * 10 + threadIdx.x] = red[0][threadIdx.x];
}

// ---------------- dense head: stage 2 (combine + dense2/3) ----------------
__global__ __launch_bounds__(64) void dense_final(
    const float* __restrict__ part,
    const float* __restrict__ B1,
    const float* __restrict__ W2, const float* __restrict__ B2,
    const float* __restrict__ W3, const float* __restrict__ B3,
    float* __restrict__ out) {
  const int b = blockIdx.x;
  __shared__ float y1[10], y2[10];
  if (threadIdx.x < 10) {
    int j = threadIdx.x;
    y1[j] = part[(b*4+0)*10 + j] + part[(b*4+1)*10 + j] +
            part[(b*4+2)*10 + j] + part[(b*4+3)*10 + j] + B1[j];
  }
  __syncthreads();
  if (threadIdx.x < 10) {
    int j = threadIdx.x;
    float s = B2[j];
#pragma unroll
    for (int i = 0; i < 10; ++i) s += y1[i] * W2[i * 10 + j];
    y2[j] = s;
  }
  __syncthreads();
  if (threadIdx.x < 10) {
    int j = threadIdx.x;
    float s = B3[j];
#pragma unroll
    for (int i = 0; i < 10; ++i) s += y2[i] * W3[i * 10 + j];
    out[b * 10 + j] = s;
  }
}

extern "C" void kernel_launch(void* const* d_in, const int* in_sizes, int n_in,
                              void* d_out, int out_size, void* d_ws, size_t ws_size,
                              hipStream_t stream) {
  const int*   inp = (const int*)d_in[0];
  const float* cw1 = (const float*)d_in[1];
  const float* cb1 = (const float*)d_in[2];
  const float* cw2 = (const float*)d_in[3];
  const float* cb2 = (const float*)d_in[4];
  const float* cw3 = (const float*)d_in[5];
  const float* cb3 = (const float*)d_in[6];
  const float* a1K = (const float*)d_in[7];
  const float* a1Q = (const float*)d_in[8];
  const float* a1V = (const float*)d_in[9];
  const float* a2K = (const float*)d_in[10];
  const float* a2Q = (const float*)d_in[11];
  const float* a2V = (const float*)d_in[12];
  const float* a3K = (const float*)d_in[13];
  const float* a3Q = (const float*)d_in[14];
  const float* a3V = (const float*)d_in[15];
  const float* dw1 = (const float*)d_in[16];
  const float* db1 = (const float*)d_in[17];
  const float* dw2 = (const float*)d_in[18];
  const float* db2 = (const float*)d_in[19];
  const float* dw3 = (const float*)d_in[20];
  const float* db3 = (const float*)d_in[21];
  float* outp = (float*)d_out;

  // workspace layout (float units)
  float* wsf = (float*)d_ws;
  float*    c2   = wsf + 5242880;               // [B,4,2048,5]   [5,242,880 .. 7,864,320)
  float*    x    = wsf + 7864320;               // [B,S,20]       [7,864,320 .. 9,175,040)
  ushort_t* qb   = (ushort_t*)(wsf);            // [B,S,32] bf16  [0 .. 1,048,576) fl
  ushort_t* kb   = (ushort_t*)(wsf + 1048576);  //                [1,048,576 .. 2,097,152)
  ushort_t* vt   = (ushort_t*)(wsf + 2097152);  // [B,32,S] bf16  [2,097,152 .. 3,145,728)
  float*    o    = wsf + 3145728;               // [B,S,20]       [3,145,728 .. 4,456,448)
  float*    part = wsf + 4456448;               // [64,4,10]      2,560 floats
  float*    w1t  = wsf + 4459008;               // [10, 20480]    204,800 floats

  conv12_kernel<<<512, 256, 0, stream>>>(inp, cw1, cb1, cw2, cb2, c2);
  conv5_kernel<2048, true><<<256, 256, 0, stream>>>(c2, cw3, cb3, x);
  transpose_w1<<<800, 256, 0, stream>>>(dw1, w1t);

  proj_kernel<<<256, 256, 0, stream>>>(x, a1K, a1Q, a1V, qb, kb, vt);
  attn_kernel<<<dim3(16, 64), 256, 0, stream>>>(qb, kb, vt, o);

  proj_kernel<<<256, 256, 0, stream>>>(o, a2K, a2Q, a2V, qb, kb, vt);
  attn_kernel<<<dim3(16, 64), 256, 0, stream>>>(qb, kb, vt, x);

  proj_kernel<<<256, 256, 0, stream>>>(x, a3K, a3Q, a3V, qb, kb, vt);
  attn_kernel<<<dim3(16, 64), 256, 0, stream>>>(qb, kb, vt, o);

  dense1_partial<<<dim3(64, 4), 256, 0, stream>>>(o, w1t, part);
  dense_final<<<64, 64, 0, stream>>>(part, db1, dw2, db2, dw3, db3, outp);
}

// Round 13
// 244.352 us; speedup vs baseline: 1.2146x; 1.0247x over previous
//
#include <hip/hip_runtime.h>
#include <hip/hip_bf16.h>

// Model: one_hot -> 3x Conv2D(5,(4,4),(1,2),SAME) -> [B,S=1024,D=20]
//        -> 3x causal self-attention -> flatten -> 3x Dense(10)
// B=64, L=8192, S=1024, D=20.
// Attention uses bf16 MFMA (16x16x32, D padded to K=32). Scores |s|<<1 ->
// streaming softmax needs no max-subtraction (exact fp32 C-frag accumulation).
// Convs/proj/dense fp32.
// R12: conv1 fused into conv2 (conv12_kernel) — bit-identical, -14 us.
// R13: conv3 fused into proj layer-1 (conv3_proj_kernel): same thread<->row
// mapping, X row kept in registers — removes 10 MB x round-trip + 1 launch.
// Accumulation orders verbatim -> output bit-identical.

#define B_ 64
#define L_ 8192
#define S_ 1024
#define D_ 20

typedef unsigned short ushort_t;
typedef __attribute__((ext_vector_type(8))) short short8_t;  // 8 bf16 (4 VGPRs)
typedef __attribute__((ext_vector_type(4))) float f32x4_t;   // MFMA C/D

__device__ __forceinline__ ushort_t f2bf(float f) {          // RNE fp32->bf16
  unsigned u = __float_as_uint(f);
  return (ushort_t)((u + 0x7fffu + ((u >> 16) & 1u)) >> 16);
}
__device__ __forceinline__ float bf2f(ushort_t h) {
  return __uint_as_float(((unsigned)h) << 16);
}

// ---------------- fused conv1+conv2 ----------------
__global__ __launch_bounds__(256) void conv12_kernel(
    const int* __restrict__ inp,
    const float* __restrict__ W1c, const float* __restrict__ B1c,
    const float* __restrict__ W2c, const float* __restrict__ B2c,
    float* __restrict__ out) {    // c2 [B,4,2048,5]
  __shared__ float w1s[80], b1s[5], w2s[400], b2s[5];
  for (int j = threadIdx.x; j < 400; j += 256) w2s[j] = W2c[j];
  if (threadIdx.x < 80)      w1s[threadIdx.x]      = W1c[threadIdx.x];
  else if (threadIdx.x < 85) b1s[threadIdx.x - 80] = B1c[threadIdx.x - 80];
  else if (threadIdx.x < 90) b2s[threadIdx.x - 85] = B2c[threadIdx.x - 85];
  __syncthreads();
  const int idx = blockIdx.x * 256 + threadIdx.x;  // 131072 total
  const int b  = idx >> 11;
  const int wo = idx & 2047;
  const int* ib = inp + (size_t)b * L_;
  int iv[10];
#pragma unroll
  for (int t = 0; t < 10; ++t) {
    int g = 4 * wo - 3 + t;
    iv[t] = (g >= 0 && g < L_) ? ib[g] : -100;   // sentinel: no kh matches
  }
  float val[4][4][5];                            // [hi][pos][ci]
#pragma unroll
  for (int pos = 0; pos < 4; ++pos) {
    const int w1 = 2 * wo - 1 + pos;
    const bool okp = (w1 >= 0 && w1 < 4096);     // conv2 SAME padding -> 0
#pragma unroll
    for (int hi = 0; hi < 4; ++hi)
#pragma unroll
      for (int ci = 0; ci < 5; ++ci) val[hi][pos][ci] = okp ? b1s[ci] : 0.f;
    if (okp) {
#pragma unroll
      for (int kw = 0; kw < 4; ++kw) {
        const int gw = 2 * w1 - 1 + kw;
        if (gw >= 0 && gw < L_) {
          const int v = iv[2 * pos + kw];
#pragma unroll
          for (int hi = 0; hi < 4; ++hi) {
            const int kh = v - hi + 1;
            if (kh >= 0 && kh < 4) {
#pragma unroll
              for (int ci = 0; ci < 5; ++ci)
                val[hi][pos][ci] += w1s[(kh * 4 + kw) * 5 + ci];
            }
          }
        }
      }
    }
  }
  float acc[4][5];
#pragma unroll
  for (int h = 0; h < 4; ++h)
#pragma unroll
    for (int c = 0; c < 5; ++c) acc[h][c] = b2s[c];
#pragma unroll
  for (int kh = 0; kh < 4; ++kh)
#pragma unroll
    for (int kw = 0; kw < 4; ++kw)
#pragma unroll
      for (int ci = 0; ci < 5; ++ci) {
        const float* wp = w2s + ((kh * 4 + kw) * 5 + ci) * 5;
        float w0 = wp[0], w1v = wp[1], w2v = wp[2], w3 = wp[3], w4 = wp[4];
#pragma unroll
        for (int h = 0; h < 4; ++h) {
          int hi = h - 1 + kh;
          if (hi >= 0 && hi < 4) {
            float x = val[hi][kw][ci];
            acc[h][0] += w0 * x;  acc[h][1] += w1v * x; acc[h][2] += w2v * x;
            acc[h][3] += w3 * x;  acc[h][4] += w4 * x;
          }
        }
      }
  float* ob = out + (size_t)b * 4 * 2048 * 5;
#pragma unroll
  for (int h = 0; h < 4; ++h)
#pragma unroll
    for (int c = 0; c < 5; ++c) ob[(h * 2048 + wo) * 5 + c] = acc[h][c];
}

// ---------------- fused conv3 + proj (layer 1) ----------------
// Thread <-> row (b, wo), wo in [0,1024). conv3 (TRANS) computes the 20-float
// X row in registers (accumulation order identical to conv5_kernel), then the
// R7-proven scalar proj runs on it (i-ascending loop, identical order).
// Outputs: Qb/Kb [r][32] bf16 (k 20..31 zero), Vt [b][32][1024] bf16 d-major.
__global__ __launch_bounds__(256) void conv3_proj_kernel(
    const float* __restrict__ in,                 // c2 [B,4,2048,5]
    const float* __restrict__ W,  const float* __restrict__ Bi,
    const float* __restrict__ Kw, const float* __restrict__ Qw,
    const float* __restrict__ Vw,
    ushort_t* __restrict__ Qb, ushort_t* __restrict__ Kb,
    ushort_t* __restrict__ Vt) {
  constexpr int WIN = 2048;
  __shared__ float ws[400], bs[5];
  __shared__ float kw[400], qw[400], vw[400];
  for (int j = threadIdx.x; j < 400; j += 256) {
    ws[j] = W[j]; kw[j] = Kw[j]; qw[j] = Qw[j]; vw[j] = Vw[j];
  }
  if (threadIdx.x < 5) bs[threadIdx.x] = Bi[threadIdx.x];
  __syncthreads();
  const int r  = blockIdx.x * 256 + threadIdx.x;  // row in [0, 65536)
  const int b  = r >> 10;
  const int wo = r & 1023;
  // conv3 input window (R7-style independent loads)
  float val[4][4][5];
#pragma unroll
  for (int hi = 0; hi < 4; ++hi) {
    const float* ir = in + ((size_t)b * 4 + hi) * WIN * 5;
#pragma unroll
    for (int kwp = 0; kwp < 4; ++kwp) {
      int wi = 2 * wo - 1 + kwp;
      bool ok = (wi >= 0 && wi < WIN);
#pragma unroll
      for (int ci = 0; ci < 5; ++ci) val[hi][kwp][ci] = ok ? ir[wi * 5 + ci] : 0.f;
    }
  }
  float acc[4][5];
#pragma unroll
  for (int h = 0; h < 4; ++h)
#pragma unroll
    for (int c = 0; c < 5; ++c) acc[h][c] = bs[c];
#pragma unroll
  for (int kh = 0; kh < 4; ++kh)
#pragma unroll
    for (int kwp = 0; kwp < 4; ++kwp)
#pragma unroll
      for (int ci = 0; ci < 5; ++ci) {
        const float* wp = ws + ((kh * 4 + kwp) * 5 + ci) * 5;
        float w0 = wp[0], w1 = wp[1], w2 = wp[2], w3 = wp[3], w4 = wp[4];
#pragma unroll
        for (int h = 0; h < 4; ++h) {
          int hi = h - 1 + kh;
          if (hi >= 0 && hi < 4) {
            float x = val[hi][kwp][ci];
            acc[h][0] += w0 * x; acc[h][1] += w1 * x; acc[h][2] += w2 * x;
            acc[h][3] += w3 * x; acc[h][4] += w4 * x;
          }
        }
      }
  // X row in registers (TRANS layout: x[h*5+c] = acc[h][c])
  float x[D_];
#pragma unroll
  for (int h = 0; h < 4; ++h)
#pragma unroll
    for (int c = 0; c < 5; ++c) x[h * 5 + c] = acc[h][c];
  // proj (verbatim math from proj_kernel)
  float q[D_], k[D_], v[D_];
#pragma unroll
  for (int j = 0; j < D_; ++j) { q[j] = 0.f; k[j] = 0.f; v[j] = 0.f; }
#pragma unroll
  for (int i = 0; i < D_; ++i) {
#pragma unroll
    for (int j = 0; j < D_; ++j) {
      q[j] += x[i] * qw[i * D_ + j];
      k[j] += x[i] * kw[i * D_ + j];
      v[j] += x[i] * vw[i * D_ + j];
    }
  }
  const float sc = 0.22360679774997896f;  // 1/sqrt(20)
  ushort_t qt[32], kt[32];
#pragma unroll
  for (int j = 0; j < D_; ++j) { qt[j] = f2bf(q[j] * sc); kt[j] = f2bf(k[j]); }
#pragma unroll
  for (int j = D_; j < 32; ++j) { qt[j] = 0; kt[j] = 0; }
  int4* qd = (int4*)(Qb + (size_t)r * 32);
  int4* kd = (int4*)(Kb + (size_t)r * 32);
#pragma unroll
  for (int j = 0; j < 4; ++j) {
    qd[j] = *(const int4*)(qt + 8 * j);
    kd[j] = *(const int4*)(kt + 8 * j);
  }
  ushort_t* vbase = Vt + ((size_t)b * 32) * 1024 + wo;
#pragma unroll
  for (int d = 0; d < D_; ++d) vbase[d * 1024] = f2bf(v[d]);
}

// ---------------- Q/K/V projection (R7-proven fp32, LDS weights) ----------
__global__ __launch_bounds__(256) void proj_kernel(
    const float* __restrict__ X,
    const float* __restrict__ Kw, const float* __restrict__ Qw,
    const float* __restrict__ Vw,
    ushort_t* __restrict__ Qb, ushort_t* __restrict__ Kb,
    ushort_t* __restrict__ Vt) {
  __shared__ float kw[400], qw[400], vw[400];
  for (int j = threadIdx.x; j < 400; j += 256) {
    kw[j] = Kw[j]; qw[j] = Qw[j]; vw[j] = Vw[j];
  }
  __syncthreads();
  int r = blockIdx.x * 256 + threadIdx.x;   // row in [0, 65536)
  const float4* xr4 = (const float4*)(X + (size_t)r * D_);
  float x[D_];
#pragma unroll
  for (int i = 0; i < 5; ++i) {
    float4 t = xr4[i];
    x[4*i] = t.x; x[4*i+1] = t.y; x[4*i+2] = t.z; x[4*i+3] = t.w;
  }
  float q[D_], k[D_], v[D_];
#pragma unroll
  for (int j = 0; j < D_; ++j) { q[j] = 0.f; k[j] = 0.f; v[j] = 0.f; }
#pragma unroll
  for (int i = 0; i < D_; ++i) {
#pragma unroll
    for (int j = 0; j < D_; ++j) {
      q[j] += x[i] * qw[i * D_ + j];
      k[j] += x[i] * kw[i * D_ + j];
      v[j] += x[i] * vw[i * D_ + j];
    }
  }
  const float sc = 0.22360679774997896f;  // 1/sqrt(20)
  ushort_t qt[32], kt[32];
#pragma unroll
  for (int j = 0; j < D_; ++j) { qt[j] = f2bf(q[j] * sc); kt[j] = f2bf(k[j]); }
#pragma unroll
  for (int j = D_; j < 32; ++j) { qt[j] = 0; kt[j] = 0; }
  int4* qd = (int4*)(Qb + (size_t)r * 32);
  int4* kd = (int4*)(Kb + (size_t)r * 32);
#pragma unroll
  for (int j = 0; j < 4; ++j) {
    qd[j] = *(const int4*)(qt + 8 * j);
    kd[j] = *(const int4*)(kt + 8 * j);
  }
  const int bb = r >> 10, ss = r & 1023;
  ushort_t* vbase = Vt + ((size_t)bb * 32) * 1024 + ss;
#pragma unroll
  for (int d = 0; d < D_; ++d) vbase[d * 1024] = f2bf(v[d]);  // coalesced across lanes
}

// ---------------- causal attention via bf16 MFMA ----------------
// (unchanged, R7-proven; see earlier rounds for layout derivation)
#define TT_ 128
__global__ __launch_bounds__(256) void attn_kernel(
    const ushort_t* __restrict__ Qb, const ushort_t* __restrict__ Kb,
    const ushort_t* __restrict__ Vt, float* __restrict__ out) {
  const int b     = blockIdx.y;
  const int strip = (blockIdx.x + 4 * (blockIdx.y >> 4)) & 15;
  const int q0    = strip * 64;
  const int tid   = threadIdx.x;
  const int w     = tid >> 6;             // wave 0..3
  const int lane  = tid & 63;
  const int n     = lane & 15;
  const int quad  = lane >> 4;
  const int qbase = q0 + 16 * w;
  __shared__ ushort_t kts[128 * 40];      // K tile, row stride 40 us (80 B)
  __shared__ ushort_t vts[32 * 136];      // V^T tile, row stride 136 us (272 B)
  __shared__ ushort_t pts[4][16 * 40];    // per-wave P scratch, stride 40 us
  const ushort_t* KbB = Kb + (size_t)b * 1024 * 32;
  const ushort_t* VtB = Vt + (size_t)b * 32 * 1024;
  short8_t qfrag = *(const short8_t*)(Qb + ((size_t)(b * 1024 + qbase + n)) * 32 + quad * 8);
  f32x4_t oA = {0.f, 0.f, 0.f, 0.f};
  f32x4_t oB = {0.f, 0.f, 0.f, 0.f};
  f32x4_t lac = {0.f, 0.f, 0.f, 0.f};
  const f32x4_t zero = {0.f, 0.f, 0.f, 0.f};
  const int Tw = qbase + 16;              // exclusive t bound for this wave
  const int nt = q0 + 64;                 // block-uniform staging bound
  ushort_t* prow = pts[w];
  for (int t0 = 0; t0 < nt; t0 += TT_) {
    __syncthreads();
    for (int i = tid; i < 512; i += 256) {
      int row = i >> 2, qc = i & 3;
      *(int4*)(kts + row * 40 + qc * 8) =
          *(const int4*)(KbB + (size_t)(t0 + row) * 32 + qc * 8);
    }
    for (int i = tid; i < 320; i += 256) {
      int row = i >> 4, cc = i & 15;
      *(int4*)(vts + row * 136 + cc * 8) =
          *(const int4*)(VtB + (size_t)row * 1024 + t0 + cc * 8);
    }
    __syncthreads();
#pragma unroll 1
    for (int cc = 0; cc < 4; ++cc) {
      const int tc = t0 + cc * 32;
      if (tc >= Tw) break;                // wave-uniform
      const short8_t kfA = *(const short8_t*)(kts + (cc * 32 + n) * 40 + quad * 8);
      const short8_t kfB = *(const short8_t*)(kts + (cc * 32 + 16 + n) * 40 + quad * 8);
      f32x4_t sA = __builtin_amdgcn_mfma_f32_16x16x32_bf16(qfrag, kfA, zero, 0, 0, 0);
      f32x4_t sB = __builtin_amdgcn_mfma_f32_16x16x32_bf16(qfrag, kfB, zero, 0, 0, 0);
#pragma unroll
      for (int r = 0; r < 4; ++r) {
        const int qg = qbase + quad * 4 + r;
        float pA = (tc + n      <= qg) ? __expf(sA[r]) : 0.f;
        float pB = (tc + 16 + n <= qg) ? __expf(sB[r]) : 0.f;
        ushort_t hA = f2bf(pA), hB = f2bf(pB);
        lac[r] += bf2f(hA) + bf2f(hB);    // consistent with bf16 P used in PV
        prow[(quad * 4 + r) * 40 + n]      = hA;
        prow[(quad * 4 + r) * 40 + 16 + n] = hB;
      }
      __asm__ volatile("s_waitcnt lgkmcnt(0)" ::: "memory");  // wave-sync LDS RAW
      short8_t pfrag = *(const short8_t*)(prow + n * 40 + quad * 8);
      const short8_t vfA = *(const short8_t*)(vts + n * 136 + cc * 32 + quad * 8);
      const short8_t vfB = *(const short8_t*)(vts + (16 + n) * 136 + cc * 32 + quad * 8);
      oA = __builtin_amdgcn_mfma_f32_16x16x32_bf16(pfrag, vfA, oA, 0, 0, 0);
      oB = __builtin_amdgcn_mfma_f32_16x16x32_bf16(pfrag, vfB, oB, 0, 0, 0);
    }
  }
#pragma unroll
  for (int m = 1; m <= 8; m <<= 1) {
#pragma unroll
    for (int r = 0; r < 4; ++r) lac[r] += __shfl_xor(lac[r], m, 64);
  }
  float* ob = out + ((size_t)(b * 1024 + qbase)) * 20;
#pragma unroll
  for (int r = 0; r < 4; ++r) {
    const float inv = 1.f / lac[r];
    const int qq = quad * 4 + r;
    ob[qq * 20 + n] = oA[r] * inv;                    // d = 0..15
    if (n < 4) ob[qq * 20 + 16 + n] = oB[r] * inv;    // d = 16..19
  }
}

// ---------------- W1 transpose (once per call) ----------------
__global__ __launch_bounds__(256) void transpose_w1(
    const float* __restrict__ W1,   // [20480, 10]
    float* __restrict__ W1T) {      // [10, 20480]
  int idx = blockIdx.x * 256 + threadIdx.x;        // 204800 total
  int j = idx / 20480;
  int i = idx % 20480;
  W1T[idx] = W1[i * 10 + j];
}

// ---------------- dense head: stage 1 (partials, vectorized) ----------------
__global__ __launch_bounds__(256) void dense1_partial(
    const float* __restrict__ X,    // [64, 20480]
    const float* __restrict__ W1T,  // [10, 20480]
    float* __restrict__ part) {     // [64, 4, 10]
  const int b = blockIdx.x;
  const int s = blockIdx.y;
  const float4* xb = (const float4*)(X + (size_t)b * 20480 + s * 5120);
  float acc[10];
#pragma unroll
  for (int j = 0; j < 10; ++j) acc[j] = 0.f;
  for (int i = threadIdx.x; i < 1280; i += 256) {
    float4 xv = xb[i];
#pragma unroll
    for (int j = 0; j < 10; ++j) {
      float4 wv = ((const float4*)(W1T + (size_t)j * 20480 + s * 5120))[i];
      acc[j] += xv.x * wv.x + xv.y * wv.y + xv.z * wv.z + xv.w * wv.w;
    }
  }
  __shared__ float red[256][10];
#pragma unroll
  for (int j = 0; j < 10; ++j) red[threadIdx.x][j] = acc[j];
  __syncthreads();
  for (int off = 128; off > 0; off >>= 1) {
    if (threadIdx.x < (unsigned)off) {
#pragma unroll
      for (int j = 0; j < 10; ++j) red[threadIdx.x][j] += red[threadIdx.x + off][j];
    }
    __syncthreads();
  }
  if (threadIdx.x < 10) part[(b * 4 + s) * 10 + threadIdx.x] = red[0][threadIdx.x];
}

// ---------------- dense head: stage 2 (combine + dense2/3) ----------------
__global__ __launch_bounds__(64) void dense_final(
    const float* __restrict__ part,
    const float* __restrict__ B1,
    const float* __restrict__ W2, const float* __restrict__ B2,
    const float* __restrict__ W3, const float* __restrict__ B3,
    float* __restrict__ out) {
  const int b = blockIdx.x;
  __shared__ float y1[10], y2[10];
  if (threadIdx.x < 10) {
    int j = threadIdx.x;
    y1[j] = part[(b*4+0)*10 + j] + part[(b*4+1)*10 + j] +
            part[(b*4+2)*10 + j] + part[(b*4+3)*10 + j] + B1[j];
  }
  __syncthreads();
  if (threadIdx.x < 10) {
    int j = threadIdx.x;
    float s = B2[j];
#pragma unroll
    for (int i = 0; i < 10; ++i) s += y1[i] * W2[i * 10 + j];
    y2[j] = s;
  }
  __syncthreads();
  if (threadIdx.x < 10) {
    int j = threadIdx.x;
    float s = B3[j];
#pragma unroll
    for (int i = 0; i < 10; ++i) s += y2[i] * W3[i * 10 + j];
    out[b * 10 + j] = s;
  }
}

extern "C" void kernel_launch(void* const* d_in, const int* in_sizes, int n_in,
                              void* d_out, int out_size, void* d_ws, size_t ws_size,
                              hipStream_t stream) {
  const int*   inp = (const int*)d_in[0];
  const float* cw1 = (const float*)d_in[1];
  const float* cb1 = (const float*)d_in[2];
  const float* cw2 = (const float*)d_in[3];
  const float* cb2 = (const float*)d_in[4];
  const float* cw3 = (const float*)d_in[5];
  const float* cb3 = (const float*)d_in[6];
  const float* a1K = (const float*)d_in[7];
  const float* a1Q = (const float*)d_in[8];
  const float* a1V = (const float*)d_in[9];
  const float* a2K = (const float*)d_in[10];
  const float* a2Q = (const float*)d_in[11];
  const float* a2V = (const float*)d_in[12];
  const float* a3K = (const float*)d_in[13];
  const float* a3Q = (const float*)d_in[14];
  const float* a3V = (const float*)d_in[15];
  const float* dw1 = (const float*)d_in[16];
  const float* db1 = (const float*)d_in[17];
  const float* dw2 = (const float*)d_in[18];
  const float* db2 = (const float*)d_in[19];
  const float* dw3 = (const float*)d_in[20];
  const float* db3 = (const float*)d_in[21];
  float* outp = (float*)d_out;

  // workspace layout (float units)
  float* wsf = (float*)d_ws;
  float*    c2   = wsf + 5242880;               // [B,4,2048,5]   [5,242,880 .. 7,864,320)
  float*    x    = wsf + 7864320;               // [B,S,20]       [7,864,320 .. 9,175,040)
  ushort_t* qb   = (ushort_t*)(wsf);            // [B,S,32] bf16  [0 .. 1,048,576) fl
  ushort_t* kb   = (ushort_t*)(wsf + 1048576);  //                [1,048,576 .. 2,097,152)
  ushort_t* vt   = (ushort_t*)(wsf + 2097152);  // [B,32,S] bf16  [2,097,152 .. 3,145,728)
  float*    o    = wsf + 3145728;               // [B,S,20]       [3,145,728 .. 4,456,448)
  float*    part = wsf + 4456448;               // [64,4,10]      2,560 floats
  float*    w1t  = wsf + 4459008;               // [10, 20480]    204,800 floats

  conv12_kernel<<<512, 256, 0, stream>>>(inp, cw1, cb1, cw2, cb2, c2);
  transpose_w1<<<800, 256, 0, stream>>>(dw1, w1t);

  conv3_proj_kernel<<<256, 256, 0, stream>>>(c2, cw3, cb3, a1K, a1Q, a1V, qb, kb, vt);
  attn_kernel<<<dim3(16, 64), 256, 0, stream>>>(qb, kb, vt, o);

  proj_kernel<<<256, 256, 0, stream>>>(o, a2K, a2Q, a2V, qb, kb, vt);
  attn_kernel<<<dim3(16, 64), 256, 0, stream>>>(qb, kb, vt, x);

  proj_kernel<<<256, 256, 0, stream>>>(x, a3K, a3Q, a3V, qb, kb, vt);
  attn_kernel<<<dim3(16, 64), 256, 0, stream>>>(qb, kb, vt, o);

  dense1_partial<<<dim3(64, 4), 256, 0, stream>>>(o, w1t, part);
  dense_final<<<64, 64, 0, stream>>>(part, db1, dw2, db2, dw3, db3, outp);
}